// Round 6
// baseline (183.698 us; speedup 1.0000x reference)
//
#include <hip/hip_runtime.h>
#include <math.h>

#define BB 4096        // batch size
#define DD 512         // repr dim
#define KTOP 9         // K+1
#define MARGIN_F 0.2f
#define NTILE 32       // 4096/128
#define NTRI (NTILE * (NTILE + 1) / 2)   // 528 upper-triangle blocks

typedef __attribute__((ext_vector_type(8))) short short8;
typedef __attribute__((ext_vector_type(4))) float f32x4;
typedef unsigned long long u64;

// split-fp32 operands (4 MB each) + per-class match bitmasks (32 KB)
__device__ unsigned short g_Rhi[(size_t)BB * DD];
__device__ unsigned short g_Rlo[(size_t)BB * DD];
__device__ u64 g_cmask[64 * 64];   // [class][lane] bit e -> label[j(lane,e)]==class

// ---- bf16 helpers (RNE) ----
__device__ __forceinline__ unsigned short f2bf(float x) {
  unsigned u = __float_as_uint(x);
  u += 0x7fffu + ((u >> 16) & 1u);
  return (unsigned short)(u >> 16);
}
__device__ __forceinline__ float bf2f(unsigned short h) {
  return __uint_as_float((unsigned)h << 16);
}

__device__ __forceinline__ void gload16(void* lds, const void* g) {
  __builtin_amdgcn_global_load_lds(
      (const __attribute__((address_space(1))) void*)g,
      (__attribute__((address_space(3))) void*)lds, 16, 0, 0);
}

// ---- key: ord(val)<<32 | (4095-j)<<1 | match   (val desc, idx asc) ----
__device__ __forceinline__ float keyval(u64 k) {
  unsigned e = (unsigned)(k >> 32);
  unsigned s = (e & 0x80000000u) ? (e ^ 0x80000000u) : ~e;
  return __uint_as_float(s);
}

__device__ __forceinline__ u64 shflxor64(u64 v, int m) {
  unsigned lo = (unsigned)v, hi = (unsigned)(v >> 32);
  lo = (unsigned)__shfl_xor((int)lo, m);
  hi = (unsigned)__shfl_xor((int)hi, m);
  return ((u64)hi << 32) | lo;
}

__device__ __forceinline__ u64 wavemax64(u64 h) {
  #pragma unroll
  for (int m = 32; m; m >>= 1) {
    u64 o = shflxor64(h, m);
    if (o > h) h = o;
  }
  return h;
}

__device__ __forceinline__ float f4c(const float4& f, int q) {
  return q == 0 ? f.x : q == 1 ? f.y : q == 2 ? f.z : f.w;
}

// ---------------- K0: split R into bf16 hi/lo ----------------
__global__ __launch_bounds__(256) void splitbf(const float* __restrict__ R) {
  const int i = (blockIdx.x * 256 + threadIdx.x) * 4;
  float4 v = *(const float4*)&R[i];
  float x[4] = {v.x, v.y, v.z, v.w};
  ushort4 h, l;
  unsigned short* hp = (unsigned short*)&h;
  unsigned short* lp = (unsigned short*)&l;
  #pragma unroll
  for (int q = 0; q < 4; ++q) {
    unsigned short hh = f2bf(x[q]);
    hp[q] = hh;
    lp[q] = f2bf(x[q] - bf2f(hh));
  }
  *(ushort4*)&g_Rhi[i] = h;
  *(ushort4*)&g_Rlo[i] = l;
}

// ---------------- K0b: row squared norms (fp32, exact) ----------------
__global__ __launch_bounds__(64) void sqnorm_kernel(const float* __restrict__ R,
                                                    float* __restrict__ sq) {
  const int row = blockIdx.x;
  const int lane = threadIdx.x;
  const float* r = R + (size_t)row * DD;
  float4 v1 = ((const float4*)r)[lane];
  float4 v2 = ((const float4*)r)[lane + 64];
  float s = v1.x*v1.x + v1.y*v1.y + v1.z*v1.z + v1.w*v1.w
          + v2.x*v2.x + v2.y*v2.y + v2.z*v2.z + v2.w*v2.w;
  #pragma unroll
  for (int off = 32; off; off >>= 1) s += __shfl_down(s, off);
  if (lane == 0) sq[row] = s;
}

// ---------------- K0c: pack labels to bytes ----------------
__global__ __launch_bounds__(256) void packlab(const int* __restrict__ labels,
                                               unsigned char* __restrict__ lab8) {
  int j = blockIdx.x * 256 + threadIdx.x;
  lab8[j] = (unsigned char)labels[j];
}

// ---------------- K0d: per-class match bitmasks ----------------
__global__ __launch_bounds__(64) void buildmask(const unsigned char* __restrict__ lab8) {
  const int c = blockIdx.x;
  const int lane = threadIdx.x;
  u64 m = 0;
  #pragma unroll
  for (int e = 0; e < 64; ++e) {
    int j = 64 * (e & ~3) + 4 * lane + (e & 3);
    m |= (u64)(lab8[j] == (unsigned char)c) << e;
  }
  g_cmask[c * 64 + lane] = m;
}

// ---------------- K1: MFMA split-bf16 GEMM, 8 waves, compact tri grid, 2-phase dbuf ----------------
// 128x128 tile, 8 waves as 2x4; each wave 64x32 output (4x2 frags of 16x16x32).
// LDS slot swizzle rides on the GLOBAL source address (dest stays linear per
// gload_lds rules); ds_read applies the same XOR.
__global__ __launch_bounds__(512) void simgemm_mfma(const int* __restrict__ labels,
                                                    const float* __restrict__ sq,
                                                    float* __restrict__ sim) {
  int tt = blockIdx.x, bi = 0, rem = NTILE;
  while (tt >= rem) { tt -= rem; --rem; ++bi; }
  const int bj = bi + tt;
  const int i0 = bi * 128, j0 = bj * 128;

  __shared__ unsigned short smem[2][4 * 4096];   // 2 x (Ahi|Alo|Bhi|Blo @ [128][32])

  const int tid = threadIdx.x;
  const int wid = tid >> 6, lane = tid & 63;
  const int wr = wid >> 2, wc = wid & 3;
  const int lrow = lane & 15, kblk = lane >> 4;

  const int r_a = lane >> 2;
  const int c_sw = (((lane & 3) ^ ((lane >> 2) & 3)) * 8);  // pre-swizzled source col

  f32x4 acc[4][2] = {};

  auto stage = [&](unsigned short* buf, int k0) {
    // each wave stages its own 16-row chunk (chunk = wid) of all 4 arrays
    const int r = wid * 16 + r_a;
    const size_t ga = (size_t)(i0 + r) * DD + k0 + c_sw;
    const size_t gb = (size_t)(j0 + r) * DD + k0 + c_sw;
    gload16(&buf[wid * 512],         &g_Rhi[ga]);
    gload16(&buf[4096 + wid * 512],  &g_Rlo[ga]);
    gload16(&buf[8192 + wid * 512],  &g_Rhi[gb]);
    gload16(&buf[12288 + wid * 512], &g_Rlo[gb]);
  };

  stage(smem[0], 0);   // prologue prefetch

  for (int step = 0; step < 16; ++step) {
    const int cur = step & 1;
    __syncthreads();   // drains vmcnt: stage(cur) landed; prev reads of cur^1 done
    if (step < 15) stage(smem[cur ^ 1], (step + 1) * 32);   // loads fly under MFMA

    unsigned short* sAhi = smem[cur];
    unsigned short* sAlo = smem[cur] + 4096;
    unsigned short* sBhi = smem[cur] + 8192;
    unsigned short* sBlo = smem[cur] + 12288;

    short8 ah[4], al[4], bh[2], bl[2];
    #pragma unroll
    for (int m = 0; m < 4; ++m) {
      const int rr = wr * 64 + m * 16 + lrow;
      const int off = rr * 32 + ((kblk ^ (lrow & 3)) * 8);
      ah[m] = *(const short8*)&sAhi[off];
      al[m] = *(const short8*)&sAlo[off];
    }
    #pragma unroll
    for (int n = 0; n < 2; ++n) {
      const int rr = wc * 32 + n * 16 + lrow;
      const int off = rr * 32 + ((kblk ^ (lrow & 3)) * 8);
      bh[n] = *(const short8*)&sBhi[off];
      bl[n] = *(const short8*)&sBlo[off];
    }
    #pragma unroll
    for (int m = 0; m < 4; ++m) {
      #pragma unroll
      for (int n = 0; n < 2; ++n) {
        acc[m][n] = __builtin_amdgcn_mfma_f32_16x16x32_bf16(ah[m], bh[n], acc[m][n], 0, 0, 0);
        acc[m][n] = __builtin_amdgcn_mfma_f32_16x16x32_bf16(ah[m], bl[n], acc[m][n], 0, 0, 0);
        acc[m][n] = __builtin_amdgcn_mfma_f32_16x16x32_bf16(al[m], bh[n], acc[m][n], 0, 0, 0);
      }
    }
  }

  __syncthreads();
  float* sqi = (float*)smem;
  float* sqj = sqi + 128;
  int* labi = (int*)(sqj + 128);
  int* labj = labi + 128;
  if (tid < 128) { sqi[tid] = sq[i0 + tid]; labi[tid] = labels[i0 + tid]; }
  else if (tid < 256) { int t2 = tid - 128; sqj[t2] = sq[j0 + t2]; labj[t2] = labels[j0 + t2]; }
  __syncthreads();

  const bool offdiag = (bi != bj);
  #pragma unroll
  for (int m = 0; m < 4; ++m) {
    const int rbase = wr * 64 + m * 16 + kblk * 4;
    #pragma unroll
    for (int n = 0; n < 2; ++n) {
      const int ccol = wc * 32 + n * 16 + lrow;
      const float sqc = sqj[ccol];
      const int lc_ = labj[ccol];
      float4 vals;
      float* vp = (float*)&vals;
      #pragma unroll
      for (int reg = 0; reg < 4; ++reg) {
        const int r = rbase + reg;
        float res = sqi[r] - 2.0f * acc[m][n][reg] + sqc;
        float dd = (res <= 0.f) ? 0.f : sqrtf(res);
        float sv = -dd + ((labi[r] != lc_) ? MARGIN_F : 0.f);
        vp[reg] = sv;
        sim[(size_t)(i0 + r) * BB + (j0 + ccol)] = sv;
      }
      if (offdiag) {
        *(float4*)&sim[(size_t)(j0 + ccol) * BB + (i0 + rbase)] = vals;
      }
    }
  }
}

// ---------------- K2: wave-per-row rank processing (rolled pops, small code) ----------------
#define EKEY(e) ({                                                             \
  float _val = f4c(v[(e) >> 2], (e) & 3);                                      \
  unsigned _su = __float_as_uint(_val);                                        \
  unsigned _ord = _su ^ ((unsigned)((int)_su >> 31) | 0x80000000u);            \
  unsigned _lo = lowbase - (unsigned)((64 * ((e) & ~3) + ((e) & 3)) << 1)      \
               + (unsigned)((mask >> (e)) & 1ull);                             \
  ((u64)_ord << 32) | _lo; })

#define TOP2UPD(k, a, b) {                                                     \
  u64 _mx = ((k) > (a)) ? (k) : (a);                                           \
  u64 _mn = ((k) > (a)) ? (a) : (k);                                           \
  (a) = _mx;                                                                   \
  (b) = (_mn > (b)) ? _mn : (b); }

__global__ __launch_bounds__(256) void rowproc4(const float* __restrict__ sim,
                                                const unsigned char* __restrict__ lab8,
                                                float* __restrict__ partials) {
  const int tid = threadIdx.x;
  const int lane = tid & 63;
  const int wv = tid >> 6;
  const int row = blockIdx.x * 4 + wv;

  __shared__ u64 sck[4][KTOP];

  const float4* rowp = (const float4*)(sim + (size_t)row * BB);
  float4 v[16];
  #pragma unroll
  for (int s = 0; s < 16; ++s) v[s] = rowp[lane + s * 64];

  const int myl = lab8[row];
  const u64 mask = g_cmask[myl * 64 + lane];
  const unsigned lowbase = 8190u - 8u * (unsigned)lane;

  // ---- per-lane top-2 + pos count ----
  u64 h1 = 0, h2 = 0;
  #pragma unroll
  for (int e = 0; e < 64; ++e) {
    u64 k = EKEY(e);
    TOP2UPD(k, h1, h2);
  }
  int pos = __popcll(mask);
  #pragma unroll
  for (int m = 32; m; m >>= 1) pos += __shfl_xor(pos, m);
  const int ks = min(pos, KTOP);

  // ---- top-ks pops (rolled loop; lazy top-2, single rescan copy) ----
  u64 kth = 0;
  float fp = 0.f; int fpn = 0;
  #pragma clang loop unroll(disable)
  for (int t = 0; t < ks; ++t) {
    u64 g = wavemax64(h1);
    if (!(g & 1ull)) { fp += keyval(g) * (1.f / log2f((float)(t + 2)) + 1.f); fpn++; }
    if (t == ks - 1) kth = g;
    if (h1 == g) {
      h1 = h2; h2 = ~0ull;
      if (h1 == ~0ull) {
        h1 = 0; h2 = 0;
        #pragma unroll
        for (int e = 0; e < 64; ++e) {
          u64 k = EKEY(e);
          if (k < g) TOP2UPD(k, h1, h2);
        }
      }
    }
  }

  // ---- fn: top-fpn same-class keys below kth, candidates stashed in LDS ----
  float fn = 0.f;
  if (fpn > 0) {
    if (lane < KTOP) sck[wv][lane] = ~0ull;
    u64 f1 = 0, f2 = 0;
    #pragma unroll
    for (int e = 0; e < 64; ++e) {
      u64 k = EKEY(e);
      if ((k & 1ull) && k < kth) TOP2UPD(k, f1, f2);
    }
    #pragma clang loop unroll(disable)
    for (int u = 0; u < fpn; ++u) {
      u64 g = wavemax64(f1);
      if (g == 0ull) break;          // uniform: no candidates left
      if (lane == 0) sck[wv][u] = g;
      if (f1 == g) {
        f1 = f2; f2 = ~0ull;
        if (f1 == ~0ull) {
          f1 = 0; f2 = 0;
          #pragma unroll
          for (int e = 0; e < 64; ++e) {
            u64 k = EKEY(e);
            if ((k & 1ull) && k < g) TOP2UPD(k, f1, f2);
          }
        }
      }
    }

    // ---- fused count pass: global rank of all candidates at once ----
    u64 ck[KTOP];
    int cnt[KTOP];
    #pragma unroll
    for (int u = 0; u < KTOP; ++u) { ck[u] = sck[wv][u]; cnt[u] = 0; }
    #pragma unroll
    for (int e = 0; e < 64; ++e) {
      u64 k = EKEY(e);
      #pragma unroll
      for (int u = 0; u < KTOP; ++u) cnt[u] += (k > ck[u]) ? 1 : 0;
    }
    #pragma unroll
    for (int u = 0; u < KTOP; ++u) {
      #pragma unroll
      for (int m = 32; m; m >>= 1) cnt[u] += __shfl_xor(cnt[u], m);
    }
    #pragma unroll
    for (int u = 0; u < KTOP; ++u) {
      if (ck[u] != ~0ull) {
        int rank = 1 + cnt[u];
        fn += keyval(ck[u]) * (1.f / log2f((float)(rank + 1)) + 1.f);
      }
    }
  }

  if (lane == 0) partials[row] = fp - fn;
}

// ---------------- K3: deterministic final reduction ----------------
__global__ __launch_bounds__(256) void finalreduce(const float* __restrict__ partials,
                                                   float* __restrict__ out) {
  __shared__ float s[256];
  const int tid = threadIdx.x;
  float acc = 0.f;
  for (int j = tid; j < BB; j += 256) acc += partials[j];
  s[tid] = acc; __syncthreads();
  #pragma unroll
  for (int st = 128; st; st >>= 1) { if (tid < st) s[tid] += s[tid + st]; __syncthreads(); }
  if (tid == 0) out[0] = s[0];
}

extern "C" void kernel_launch(void* const* d_in, const int* in_sizes, int n_in,
                              void* d_out, int out_size, void* d_ws, size_t ws_size,
                              hipStream_t stream) {
  const float* R      = (const float*)d_in[0];
  const int*   labels = (const int*)d_in[1];
  float* out = (float*)d_out;

  float* sim            = (float*)d_ws;                                  // 64 MB
  float* sq             = (float*)((char*)d_ws + (size_t)BB * BB * 4);   // 16 KB
  float* partials       = sq + BB;                                       // 16 KB
  unsigned char* lab8   = (unsigned char*)(partials + BB);               // 4 KB

  splitbf<<<(BB * DD) / (256 * 4), 256, 0, stream>>>(R);
  sqnorm_kernel<<<BB, 64, 0, stream>>>(R, sq);
  packlab<<<BB / 256, 256, 0, stream>>>(labels, lab8);
  buildmask<<<64, 64, 0, stream>>>(lab8);
  simgemm_mfma<<<NTRI, 512, 0, stream>>>(labels, sq, sim);
  rowproc4<<<BB / 4, 256, 0, stream>>>(sim, lab8, partials);
  finalreduce<<<1, 256, 0, stream>>>(partials, out);
}

// Round 7
// 135.971 us; speedup vs baseline: 1.3510x; 1.3510x over previous
//
#include <hip/hip_runtime.h>
#include <math.h>

#define BB 4096        // batch size
#define DD 512         // repr dim
#define KTOP 9         // K+1
#define MARGIN_F 0.2f
#define NT64 64        // 4096/64
#define NTRI64 (NT64 * (NT64 + 1) / 2)   // 2080 upper-triangle blocks

typedef __attribute__((ext_vector_type(8))) short short8;
typedef __attribute__((ext_vector_type(4))) float f32x4;
typedef unsigned long long u64;

// split-fp32 operands (4 MB each) + per-class match bitmasks (32 KB)
__device__ unsigned short g_Rhi[(size_t)BB * DD];
__device__ unsigned short g_Rlo[(size_t)BB * DD];
__device__ u64 g_cmask[64 * 64];   // [class][lane] bit e -> label[j(lane,e)]==class

// ---- bf16 helpers (RNE) ----
__device__ __forceinline__ unsigned short f2bf(float x) {
  unsigned u = __float_as_uint(x);
  u += 0x7fffu + ((u >> 16) & 1u);
  return (unsigned short)(u >> 16);
}
__device__ __forceinline__ float bf2f(unsigned short h) {
  return __uint_as_float((unsigned)h << 16);
}

__device__ __forceinline__ void gload16(void* lds, const void* g) {
  __builtin_amdgcn_global_load_lds(
      (const __attribute__((address_space(1))) void*)g,
      (__attribute__((address_space(3))) void*)lds, 16, 0, 0);
}

// ---- key: ord(val)<<32 | (4095-j)<<1 | match   (val desc, idx asc) ----
__device__ __forceinline__ float keyval(u64 k) {
  unsigned e = (unsigned)(k >> 32);
  unsigned s = (e & 0x80000000u) ? (e ^ 0x80000000u) : ~e;
  return __uint_as_float(s);
}

__device__ __forceinline__ u64 shflxor64(u64 v, int m) {
  unsigned lo = (unsigned)v, hi = (unsigned)(v >> 32);
  lo = (unsigned)__shfl_xor((int)lo, m);
  hi = (unsigned)__shfl_xor((int)hi, m);
  return ((u64)hi << 32) | lo;
}

__device__ __forceinline__ u64 wavemax64(u64 h) {
  #pragma unroll
  for (int m = 32; m; m >>= 1) {
    u64 o = shflxor64(h, m);
    if (o > h) h = o;
  }
  return h;
}

__device__ __forceinline__ unsigned u4c(const uint4& f, int q) {
  return q == 0 ? f.x : q == 1 ? f.y : q == 2 ? f.z : f.w;
}

// ---------------- K0: split R into bf16 hi/lo ----------------
__global__ __launch_bounds__(256) void splitbf(const float* __restrict__ R) {
  const int i = (blockIdx.x * 256 + threadIdx.x) * 4;
  float4 v = *(const float4*)&R[i];
  float x[4] = {v.x, v.y, v.z, v.w};
  ushort4 h, l;
  unsigned short* hp = (unsigned short*)&h;
  unsigned short* lp = (unsigned short*)&l;
  #pragma unroll
  for (int q = 0; q < 4; ++q) {
    unsigned short hh = f2bf(x[q]);
    hp[q] = hh;
    lp[q] = f2bf(x[q] - bf2f(hh));
  }
  *(ushort4*)&g_Rhi[i] = h;
  *(ushort4*)&g_Rlo[i] = l;
}

// ---------------- K0b: row squared norms (fp32, exact) ----------------
__global__ __launch_bounds__(64) void sqnorm_kernel(const float* __restrict__ R,
                                                    float* __restrict__ sq) {
  const int row = blockIdx.x;
  const int lane = threadIdx.x;
  const float* r = R + (size_t)row * DD;
  float4 v1 = ((const float4*)r)[lane];
  float4 v2 = ((const float4*)r)[lane + 64];
  float s = v1.x*v1.x + v1.y*v1.y + v1.z*v1.z + v1.w*v1.w
          + v2.x*v2.x + v2.y*v2.y + v2.z*v2.z + v2.w*v2.w;
  #pragma unroll
  for (int off = 32; off; off >>= 1) s += __shfl_down(s, off);
  if (lane == 0) sq[row] = s;
}

// ---------------- K0c: pack labels to bytes ----------------
__global__ __launch_bounds__(256) void packlab(const int* __restrict__ labels,
                                               unsigned char* __restrict__ lab8) {
  int j = blockIdx.x * 256 + threadIdx.x;
  lab8[j] = (unsigned char)labels[j];
}

// ---------------- K0d: per-class match bitmasks ----------------
__global__ __launch_bounds__(64) void buildmask(const unsigned char* __restrict__ lab8) {
  const int c = blockIdx.x;
  const int lane = threadIdx.x;
  u64 m = 0;
  #pragma unroll
  for (int e = 0; e < 64; ++e) {
    int j = 64 * (e & ~3) + 4 * lane + (e & 3);
    m |= (u64)(lab8[j] == (unsigned char)c) << e;
  }
  g_cmask[c * 64 + lane] = m;
}

// ---------------- K1: MFMA 2-term split-bf16 GEMM, 64x64 tiles, tri grid ----------------
// dot ~= ah.(bh+bl): A-side hi only (error ~|al.b| ~ 0.05 per dot, sim err ~2e-3,
// vastly under the 4239 absmax budget). 2080 blocks -> 8.1/CU (tail 11% vs 45%),
// LDS 24 KB dbuf -> 6 blocks/CU. Swizzle rides on the GLOBAL source col (dest
// linear per gload_lds rules); ds_read applies the same XOR.
__global__ __launch_bounds__(256) void simgemm_mfma(const int* __restrict__ labels,
                                                    const float* __restrict__ sq,
                                                    float* __restrict__ sim) {
  int tt = blockIdx.x, bi = 0, rem = NT64;
  while (tt >= rem) { tt -= rem; --rem; ++bi; }
  const int bj = bi + tt;
  const int i0 = bi * 64, j0 = bj * 64;

  __shared__ unsigned short smem[2][3 * 2048];   // 2 x (Ahi|Bhi|Blo @ [64][32])

  const int tid = threadIdx.x;
  const int wid = tid >> 6, lane = tid & 63;
  const int wr = wid >> 1, wc = wid & 1;
  const int lrow = lane & 15, kblk = lane >> 4;

  const int r_a = lane >> 2;                       // 0..15
  const int c_sw = (((lane & 3) ^ (r_a & 3)) * 8); // pre-swizzled source col

  f32x4 acc[2][2] = {};

  auto stage = [&](unsigned short* buf, int k0) {
    const int r = wid * 16 + r_a;
    const size_t ga = (size_t)(i0 + r) * DD + k0 + c_sw;
    const size_t gb = (size_t)(j0 + r) * DD + k0 + c_sw;
    gload16(&buf[wid * 512],        &g_Rhi[ga]);   // Ahi
    gload16(&buf[2048 + wid * 512], &g_Rhi[gb]);   // Bhi
    gload16(&buf[4096 + wid * 512], &g_Rlo[gb]);   // Blo
  };

  stage(smem[0], 0);   // prologue prefetch

  for (int step = 0; step < 16; ++step) {
    const int cur = step & 1;
    __syncthreads();   // drains vmcnt: stage(cur) landed; prev reads of cur^1 done
    if (step < 15) stage(smem[cur ^ 1], (step + 1) * 32);   // loads fly under MFMA

    unsigned short* sAhi = smem[cur];
    unsigned short* sBhi = smem[cur] + 2048;
    unsigned short* sBlo = smem[cur] + 4096;

    short8 ah[2], bh[2], bl[2];
    #pragma unroll
    for (int m = 0; m < 2; ++m) {
      const int rr = wr * 32 + m * 16 + lrow;
      const int off = rr * 32 + ((kblk ^ (lrow & 3)) * 8);
      ah[m] = *(const short8*)&sAhi[off];
    }
    #pragma unroll
    for (int n = 0; n < 2; ++n) {
      const int rr = wc * 32 + n * 16 + lrow;
      const int off = rr * 32 + ((kblk ^ (lrow & 3)) * 8);
      bh[n] = *(const short8*)&sBhi[off];
      bl[n] = *(const short8*)&sBlo[off];
    }
    #pragma unroll
    for (int m = 0; m < 2; ++m) {
      #pragma unroll
      for (int n = 0; n < 2; ++n) {
        acc[m][n] = __builtin_amdgcn_mfma_f32_16x16x32_bf16(ah[m], bh[n], acc[m][n], 0, 0, 0);
        acc[m][n] = __builtin_amdgcn_mfma_f32_16x16x32_bf16(ah[m], bl[n], acc[m][n], 0, 0, 0);
      }
    }
  }

  __syncthreads();
  float* sqi = (float*)smem;
  float* sqj = sqi + 64;
  int* labi = (int*)(sqj + 64);
  int* labj = labi + 64;
  if (tid < 64) { sqi[tid] = sq[i0 + tid]; labi[tid] = labels[i0 + tid]; }
  else if (tid < 128) { int t2 = tid - 64; sqj[t2] = sq[j0 + t2]; labj[t2] = labels[j0 + t2]; }
  __syncthreads();

  const bool offdiag = (bi != bj);
  #pragma unroll
  for (int m = 0; m < 2; ++m) {
    const int rbase = wr * 32 + m * 16 + kblk * 4;
    #pragma unroll
    for (int n = 0; n < 2; ++n) {
      const int ccol = wc * 32 + n * 16 + lrow;
      const float sqc = sqj[ccol];
      const int lc_ = labj[ccol];
      float4 vals;
      float* vp = (float*)&vals;
      #pragma unroll
      for (int reg = 0; reg < 4; ++reg) {
        const int r = rbase + reg;
        float res = sqi[r] - 2.0f * acc[m][n][reg] + sqc;
        float dd = (res <= 0.f) ? 0.f : sqrtf(res);
        float sv = -dd + ((labi[r] != lc_) ? MARGIN_F : 0.f);
        vp[reg] = sv;
        sim[(size_t)(i0 + r) * BB + (j0 + ccol)] = sv;
      }
      if (offdiag) {
        *(float4*)&sim[(size_t)(j0 + ccol) * BB + (i0 + rbase)] = vals;
      }
    }
  }
}

// ---------------- K2: wave-per-row rank processing (unrolled, ord precomputed) ----------------
// Element e (0..63) of lane: j = 64*(e&~3) + 4*lane + (e&3).
// v[] holds the monotone ord transform of sim (computed once at load);
// key = ord<<32 | (4095-j)<<1 | match.
#define EKEY(e) (((u64)u4c(v[(e) >> 2], (e) & 3) << 32) |                      \
                 (unsigned)(lowbase - (unsigned)((64 * ((e) & ~3) + ((e) & 3)) << 1) \
                          + (unsigned)((mask >> (e)) & 1ull)))

#define TOP2UPD(k, a, b) {                                                     \
  u64 _mx = ((k) > (a)) ? (k) : (a);                                           \
  u64 _mn = ((k) > (a)) ? (a) : (k);                                           \
  (a) = _mx;                                                                   \
  (b) = (_mn > (b)) ? _mn : (b); }

__global__ __launch_bounds__(64) void rowproc3(const float* __restrict__ sim,
                                               const unsigned char* __restrict__ lab8,
                                               float* __restrict__ partials) {
  const int lane = threadIdx.x;
  const int row = blockIdx.x;

  const uint4* rowp = (const uint4*)(sim + (size_t)row * BB);
  uint4 v[16];
  #pragma unroll
  for (int s = 0; s < 16; ++s) {
    uint4 w = rowp[lane + s * 64];
    w.x = w.x ^ ((unsigned)((int)w.x >> 31) | 0x80000000u);
    w.y = w.y ^ ((unsigned)((int)w.y >> 31) | 0x80000000u);
    w.z = w.z ^ ((unsigned)((int)w.z >> 31) | 0x80000000u);
    w.w = w.w ^ ((unsigned)((int)w.w >> 31) | 0x80000000u);
    v[s] = w;
  }

  const int myl = lab8[row];
  const u64 mask = g_cmask[myl * 64 + lane];
  const unsigned lowbase = 8190u - 8u * (unsigned)lane;

  u64 h1 = 0, h2 = 0;
  #pragma unroll
  for (int e = 0; e < 64; ++e) {
    u64 k = EKEY(e);
    TOP2UPD(k, h1, h2);
  }
  int pos = __popcll(mask);
  #pragma unroll
  for (int m = 32; m; m >>= 1) pos += __shfl_xor(pos, m);
  const int ks = min(pos, KTOP);

  u64 kth = 0;
  float fp = 0.f; int fpn = 0;
  #pragma unroll
  for (int t = 0; t < KTOP; ++t) {
    if (t < ks) {
      u64 g = wavemax64(h1);
      if (!(g & 1ull)) { fp += keyval(g) * (1.f / log2f((float)(t + 2)) + 1.f); fpn++; }
      if (t == ks - 1) kth = g;
      if (h1 == g) {
        h1 = h2; h2 = ~0ull;
        if (h1 == ~0ull) {
          h1 = 0; h2 = 0;
          #pragma unroll
          for (int e = 0; e < 64; ++e) {
            u64 k = EKEY(e);
            if (k < g) TOP2UPD(k, h1, h2);
          }
        }
      }
    }
  }

  float fn = 0.f;
  if (fpn > 0) {
    u64 f1 = 0, f2 = 0;
    #pragma unroll
    for (int e = 0; e < 64; ++e) {
      u64 k = EKEY(e);
      if ((k & 1ull) && k < kth) TOP2UPD(k, f1, f2);
    }
    u64 ck[KTOP];
    int nc = 0;
    #pragma unroll
    for (int u = 0; u < KTOP; ++u) {
      ck[u] = ~0ull;
      if (u < fpn) {
        u64 g = wavemax64(f1);
        if (g != 0ull) {
          ck[u] = g; nc = u + 1;
          if (f1 == g) {
            f1 = f2; f2 = ~0ull;
            if (f1 == ~0ull) {
              f1 = 0; f2 = 0;
              #pragma unroll
              for (int e = 0; e < 64; ++e) {
                u64 k = EKEY(e);
                if ((k & 1ull) && k < g) TOP2UPD(k, f1, f2);
              }
            }
          }
        }
      }
    }
    if (nc > 0) {
      int cnt[KTOP];
      #pragma unroll
      for (int u = 0; u < KTOP; ++u) cnt[u] = 0;
      #pragma unroll
      for (int e = 0; e < 64; ++e) {
        u64 k = EKEY(e);
        #pragma unroll
        for (int u = 0; u < KTOP; ++u) cnt[u] += (k > ck[u]) ? 1 : 0;
      }
      #pragma unroll
      for (int u = 0; u < KTOP; ++u) {
        #pragma unroll
        for (int m = 32; m; m >>= 1) cnt[u] += __shfl_xor(cnt[u], m);
      }
      #pragma unroll
      for (int u = 0; u < KTOP; ++u) {
        if (u < nc) {
          int rank = 1 + cnt[u];
          fn += keyval(ck[u]) * (1.f / log2f((float)(rank + 1)) + 1.f);
        }
      }
    }
  }

  if (lane == 0) partials[row] = fp - fn;
}

// ---------------- K3: deterministic final reduction ----------------
__global__ __launch_bounds__(256) void finalreduce(const float* __restrict__ partials,
                                                   float* __restrict__ out) {
  __shared__ float s[256];
  const int tid = threadIdx.x;
  float acc = 0.f;
  for (int j = tid; j < BB; j += 256) acc += partials[j];
  s[tid] = acc; __syncthreads();
  #pragma unroll
  for (int st = 128; st; st >>= 1) { if (tid < st) s[tid] += s[tid + st]; __syncthreads(); }
  if (tid == 0) out[0] = s[0];
}

extern "C" void kernel_launch(void* const* d_in, const int* in_sizes, int n_in,
                              void* d_out, int out_size, void* d_ws, size_t ws_size,
                              hipStream_t stream) {
  const float* R      = (const float*)d_in[0];
  const int*   labels = (const int*)d_in[1];
  float* out = (float*)d_out;

  float* sim            = (float*)d_ws;                                  // 64 MB
  float* sq             = (float*)((char*)d_ws + (size_t)BB * BB * 4);   // 16 KB
  float* partials       = sq + BB;                                       // 16 KB
  unsigned char* lab8   = (unsigned char*)(partials + BB);               // 4 KB

  splitbf<<<(BB * DD) / (256 * 4), 256, 0, stream>>>(R);
  sqnorm_kernel<<<BB, 64, 0, stream>>>(R, sq);
  packlab<<<BB / 256, 256, 0, stream>>>(labels, lab8);
  buildmask<<<64, 64, 0, stream>>>(lab8);
  simgemm_mfma<<<NTRI64, 256, 0, stream>>>(labels, sq, sim);
  rowproc3<<<BB, 64, 0, stream>>>(sim, lab8, partials);
  finalreduce<<<1, 256, 0, stream>>>(partials, out);
}

// Round 8
// 134.138 us; speedup vs baseline: 1.3695x; 1.0137x over previous
//
#include <hip/hip_runtime.h>
#include <math.h>

#define BB 4096        // batch size
#define DD 512         // repr dim
#define KTOP 9         // K+1
#define MARGIN_F 0.2f
#define NT64 64        // 4096/64
#define NTRI64 (NT64 * (NT64 + 1) / 2)   // 2080 upper-triangle blocks

typedef __attribute__((ext_vector_type(8))) short short8;
typedef __attribute__((ext_vector_type(4))) float f32x4;
typedef unsigned long long u64;

// split-fp32 operands (4 MB each) + per-class match bitmasks (32 KB)
__device__ unsigned short g_Rhi[(size_t)BB * DD];
__device__ unsigned short g_Rlo[(size_t)BB * DD];
__device__ u64 g_cmask[64 * 64];   // [class][lane] bit e -> label[j(lane,e)]==class

// ---- bf16 helpers (RNE) ----
__device__ __forceinline__ unsigned short f2bf(float x) {
  unsigned u = __float_as_uint(x);
  u += 0x7fffu + ((u >> 16) & 1u);
  return (unsigned short)(u >> 16);
}
__device__ __forceinline__ float bf2f(unsigned short h) {
  return __uint_as_float((unsigned)h << 16);
}

__device__ __forceinline__ void gload16(void* lds, const void* g) {
  __builtin_amdgcn_global_load_lds(
      (const __attribute__((address_space(1))) void*)g,
      (__attribute__((address_space(3))) void*)lds, 16, 0, 0);
}

// ---- key: ord(val)<<32 | (4095-j)<<1 | match   (val desc, idx asc) ----
__device__ __forceinline__ float keyval(u64 k) {
  unsigned e = (unsigned)(k >> 32);
  unsigned s = (e & 0x80000000u) ? (e ^ 0x80000000u) : ~e;
  return __uint_as_float(s);
}

// ---- DPP wave reductions (VALU-speed; no LDS/ds_swizzle round-trips) ----
// butterfly within row16: quad_perm xor1 (0xB1), xor2 (0x4E), half_mirror
// (0x141), mirror (0x140); then row_bcast15 (0x142, rm 0xa) and row_bcast31
// (0x143, rm 0xc) push partials up; lane 63 holds the total -> readlane.
__device__ __forceinline__ u64 wavemax64_dpp(u64 h) {
  unsigned lo = (unsigned)h, hi = (unsigned)(h >> 32);
#define MSTEP(CTRL, RM)                                                        \
  {                                                                            \
    unsigned lo2 = (unsigned)__builtin_amdgcn_update_dpp(0, (int)lo, CTRL, RM, 0xf, false); \
    unsigned hi2 = (unsigned)__builtin_amdgcn_update_dpp(0, (int)hi, CTRL, RM, 0xf, false); \
    u64 c = ((u64)hi << 32) | lo, o = ((u64)hi2 << 32) | lo2;                  \
    if (o > c) c = o;                                                          \
    lo = (unsigned)c; hi = (unsigned)(c >> 32);                                \
  }
  MSTEP(0xB1, 0xf) MSTEP(0x4E, 0xf) MSTEP(0x141, 0xf) MSTEP(0x140, 0xf)
  MSTEP(0x142, 0xa) MSTEP(0x143, 0xc)
#undef MSTEP
  unsigned glo = (unsigned)__builtin_amdgcn_readlane((int)lo, 63);
  unsigned ghi = (unsigned)__builtin_amdgcn_readlane((int)hi, 63);
  return ((u64)ghi << 32) | glo;
}

__device__ __forceinline__ int wavesum_dpp(int c) {
#define SSTEP(CTRL, RM)                                                        \
  c += __builtin_amdgcn_update_dpp(0, c, CTRL, RM, 0xf, false);
  SSTEP(0xB1, 0xf) SSTEP(0x4E, 0xf) SSTEP(0x141, 0xf) SSTEP(0x140, 0xf)
  SSTEP(0x142, 0xa) SSTEP(0x143, 0xc)
#undef SSTEP
  return __builtin_amdgcn_readlane(c, 63);
}

__device__ __forceinline__ unsigned u4c(const uint4& f, int q) {
  return q == 0 ? f.x : q == 1 ? f.y : q == 2 ? f.z : f.w;
}

// ---------------- K0: split R into bf16 hi/lo ----------------
__global__ __launch_bounds__(256) void splitbf(const float* __restrict__ R) {
  const int i = (blockIdx.x * 256 + threadIdx.x) * 4;
  float4 v = *(const float4*)&R[i];
  float x[4] = {v.x, v.y, v.z, v.w};
  ushort4 h, l;
  unsigned short* hp = (unsigned short*)&h;
  unsigned short* lp = (unsigned short*)&l;
  #pragma unroll
  for (int q = 0; q < 4; ++q) {
    unsigned short hh = f2bf(x[q]);
    hp[q] = hh;
    lp[q] = f2bf(x[q] - bf2f(hh));
  }
  *(ushort4*)&g_Rhi[i] = h;
  *(ushort4*)&g_Rlo[i] = l;
}

// ---------------- K0b: row squared norms (fp32, exact) ----------------
__global__ __launch_bounds__(64) void sqnorm_kernel(const float* __restrict__ R,
                                                    float* __restrict__ sq) {
  const int row = blockIdx.x;
  const int lane = threadIdx.x;
  const float* r = R + (size_t)row * DD;
  float4 v1 = ((const float4*)r)[lane];
  float4 v2 = ((const float4*)r)[lane + 64];
  float s = v1.x*v1.x + v1.y*v1.y + v1.z*v1.z + v1.w*v1.w
          + v2.x*v2.x + v2.y*v2.y + v2.z*v2.z + v2.w*v2.w;
  #pragma unroll
  for (int off = 32; off; off >>= 1) s += __shfl_down(s, off);
  if (lane == 0) sq[row] = s;
}

// ---------------- K0c: pack labels to bytes ----------------
__global__ __launch_bounds__(256) void packlab(const int* __restrict__ labels,
                                               unsigned char* __restrict__ lab8) {
  int j = blockIdx.x * 256 + threadIdx.x;
  lab8[j] = (unsigned char)labels[j];
}

// ---------------- K0d: per-class match bitmasks ----------------
__global__ __launch_bounds__(64) void buildmask(const unsigned char* __restrict__ lab8) {
  const int c = blockIdx.x;
  const int lane = threadIdx.x;
  u64 m = 0;
  #pragma unroll
  for (int e = 0; e < 64; ++e) {
    int j = 64 * (e & ~3) + 4 * lane + (e & 3);
    m |= (u64)(lab8[j] == (unsigned char)c) << e;
  }
  g_cmask[c * 64 + lane] = m;
}

// ---------------- K1: MFMA 2-term split-bf16 GEMM, 64x64 tiles, tri grid ----------------
// XCD-chunked swizzle: 2080 = 8*260 exactly; consecutive tri-indices (sharing
// A-panels) land on the same XCD -> A-panel L2 locality.
__global__ __launch_bounds__(256) void simgemm_mfma(const int* __restrict__ labels,
                                                    const float* __restrict__ sq,
                                                    float* __restrict__ sim) {
  const int bid = blockIdx.x;
  int tt = (bid & 7) * (NTRI64 / 8) + (bid >> 3);   // bijective XCD chunk map
  int bi = 0, rem = NT64;
  while (tt >= rem) { tt -= rem; --rem; ++bi; }
  const int bj = bi + tt;
  const int i0 = bi * 64, j0 = bj * 64;

  __shared__ unsigned short smem[2][3 * 2048];   // 2 x (Ahi|Bhi|Blo @ [64][32])

  const int tid = threadIdx.x;
  const int wid = tid >> 6, lane = tid & 63;
  const int wr = wid >> 1, wc = wid & 1;
  const int lrow = lane & 15, kblk = lane >> 4;

  const int r_a = lane >> 2;                       // 0..15
  const int c_sw = (((lane & 3) ^ (r_a & 3)) * 8); // pre-swizzled source col

  f32x4 acc[2][2] = {};

  auto stage = [&](unsigned short* buf, int k0) {
    const int r = wid * 16 + r_a;
    const size_t ga = (size_t)(i0 + r) * DD + k0 + c_sw;
    const size_t gb = (size_t)(j0 + r) * DD + k0 + c_sw;
    gload16(&buf[wid * 512],        &g_Rhi[ga]);   // Ahi
    gload16(&buf[2048 + wid * 512], &g_Rhi[gb]);   // Bhi
    gload16(&buf[4096 + wid * 512], &g_Rlo[gb]);   // Blo
  };

  stage(smem[0], 0);   // prologue prefetch

  for (int step = 0; step < 16; ++step) {
    const int cur = step & 1;
    __syncthreads();   // drains vmcnt: stage(cur) landed; prev reads of cur^1 done
    if (step < 15) stage(smem[cur ^ 1], (step + 1) * 32);   // loads fly under MFMA

    unsigned short* sAhi = smem[cur];
    unsigned short* sBhi = smem[cur] + 2048;
    unsigned short* sBlo = smem[cur] + 4096;

    short8 ah[2], bh[2], bl[2];
    #pragma unroll
    for (int m = 0; m < 2; ++m) {
      const int rr = wr * 32 + m * 16 + lrow;
      const int off = rr * 32 + ((kblk ^ (lrow & 3)) * 8);
      ah[m] = *(const short8*)&sAhi[off];
    }
    #pragma unroll
    for (int n = 0; n < 2; ++n) {
      const int rr = wc * 32 + n * 16 + lrow;
      const int off = rr * 32 + ((kblk ^ (lrow & 3)) * 8);
      bh[n] = *(const short8*)&sBhi[off];
      bl[n] = *(const short8*)&sBlo[off];
    }
    #pragma unroll
    for (int m = 0; m < 2; ++m) {
      #pragma unroll
      for (int n = 0; n < 2; ++n) {
        acc[m][n] = __builtin_amdgcn_mfma_f32_16x16x32_bf16(ah[m], bh[n], acc[m][n], 0, 0, 0);
        acc[m][n] = __builtin_amdgcn_mfma_f32_16x16x32_bf16(ah[m], bl[n], acc[m][n], 0, 0, 0);
      }
    }
  }

  __syncthreads();
  float* sqi = (float*)smem;
  float* sqj = sqi + 64;
  int* labi = (int*)(sqj + 64);
  int* labj = labi + 64;
  if (tid < 64) { sqi[tid] = sq[i0 + tid]; labi[tid] = labels[i0 + tid]; }
  else if (tid < 128) { int t2 = tid - 64; sqj[t2] = sq[j0 + t2]; labj[t2] = labels[j0 + t2]; }
  __syncthreads();

  const bool offdiag = (bi != bj);
  #pragma unroll
  for (int m = 0; m < 2; ++m) {
    const int rbase = wr * 32 + m * 16 + kblk * 4;
    #pragma unroll
    for (int n = 0; n < 2; ++n) {
      const int ccol = wc * 32 + n * 16 + lrow;
      const float sqc = sqj[ccol];
      const int lc_ = labj[ccol];
      float4 vals;
      float* vp = (float*)&vals;
      #pragma unroll
      for (int reg = 0; reg < 4; ++reg) {
        const int r = rbase + reg;
        float res = sqi[r] - 2.0f * acc[m][n][reg] + sqc;
        float dd = (res <= 0.f) ? 0.f : sqrtf(res);
        float sv = -dd + ((labi[r] != lc_) ? MARGIN_F : 0.f);
        vp[reg] = sv;
        sim[(size_t)(i0 + r) * BB + (j0 + ccol)] = sv;
      }
      if (offdiag) {
        *(float4*)&sim[(size_t)(j0 + ccol) * BB + (i0 + rbase)] = vals;
      }
    }
  }
}

// ---------------- K2: wave-per-row rank processing (DPP reduces) ----------------
// Element e (0..63) of lane: j = 64*(e&~3) + 4*lane + (e&3).
// v[] holds the monotone ord transform of sim (computed once at load);
// key = ord<<32 | (4095-j)<<1 | match.
#define EKEY(e) (((u64)u4c(v[(e) >> 2], (e) & 3) << 32) |                      \
                 (unsigned)(lowbase - (unsigned)((64 * ((e) & ~3) + ((e) & 3)) << 1) \
                          + (unsigned)((mask >> (e)) & 1ull)))

#define TOP2UPD(k, a, b) {                                                     \
  u64 _mx = ((k) > (a)) ? (k) : (a);                                           \
  u64 _mn = ((k) > (a)) ? (a) : (k);                                           \
  (a) = _mx;                                                                   \
  (b) = (_mn > (b)) ? _mn : (b); }

__global__ __launch_bounds__(256) void rowproc5(const float* __restrict__ sim,
                                                const unsigned char* __restrict__ lab8,
                                                float* __restrict__ partials) {
  const int tid = threadIdx.x;
  const int lane = tid & 63;
  const int row = blockIdx.x * 4 + (tid >> 6);

  const uint4* rowp = (const uint4*)(sim + (size_t)row * BB);
  uint4 v[16];
  #pragma unroll
  for (int s = 0; s < 16; ++s) {
    uint4 w = rowp[lane + s * 64];
    w.x = w.x ^ ((unsigned)((int)w.x >> 31) | 0x80000000u);
    w.y = w.y ^ ((unsigned)((int)w.y >> 31) | 0x80000000u);
    w.z = w.z ^ ((unsigned)((int)w.z >> 31) | 0x80000000u);
    w.w = w.w ^ ((unsigned)((int)w.w >> 31) | 0x80000000u);
    v[s] = w;
  }

  const int myl = lab8[row];
  const u64 mask = g_cmask[myl * 64 + lane];
  const unsigned lowbase = 8190u - 8u * (unsigned)lane;

  u64 h1 = 0, h2 = 0;
  #pragma unroll
  for (int e = 0; e < 64; ++e) {
    u64 k = EKEY(e);
    TOP2UPD(k, h1, h2);
  }
  const int pos = wavesum_dpp(__popcll(mask));
  const int ks = min(pos, KTOP);

  u64 kth = 0;
  float fp = 0.f; int fpn = 0;
  #pragma unroll
  for (int t = 0; t < KTOP; ++t) {
    if (t < ks) {
      u64 g = wavemax64_dpp(h1);
      if (!(g & 1ull)) { fp += keyval(g) * (1.f / log2f((float)(t + 2)) + 1.f); fpn++; }
      if (t == ks - 1) kth = g;
      if (h1 == g) {
        h1 = h2; h2 = ~0ull;
        if (h1 == ~0ull) {
          h1 = 0; h2 = 0;
          #pragma unroll
          for (int e = 0; e < 64; ++e) {
            u64 k = EKEY(e);
            if (k < g) TOP2UPD(k, h1, h2);
          }
        }
      }
    }
  }

  float fn = 0.f;
  if (fpn > 0) {
    u64 f1 = 0, f2 = 0;
    #pragma unroll
    for (int e = 0; e < 64; ++e) {
      u64 k = EKEY(e);
      if ((k & 1ull) && k < kth) TOP2UPD(k, f1, f2);
    }
    u64 ck[KTOP];
    int nc = 0;
    #pragma unroll
    for (int u = 0; u < KTOP; ++u) {
      ck[u] = ~0ull;
      if (u < fpn) {
        u64 g = wavemax64_dpp(f1);
        if (g != 0ull) {
          ck[u] = g; nc = u + 1;
          if (f1 == g) {
            f1 = f2; f2 = ~0ull;
            if (f1 == ~0ull) {
              f1 = 0; f2 = 0;
              #pragma unroll
              for (int e = 0; e < 64; ++e) {
                u64 k = EKEY(e);
                if ((k & 1ull) && k < g) TOP2UPD(k, f1, f2);
              }
            }
          }
        }
      }
    }
    if (nc > 0) {
      int cnt[KTOP];
      #pragma unroll
      for (int u = 0; u < KTOP; ++u) cnt[u] = 0;
      #pragma unroll
      for (int e = 0; e < 64; ++e) {
        u64 k = EKEY(e);
        #pragma unroll
        for (int u = 0; u < KTOP; ++u) cnt[u] += (k > ck[u]) ? 1 : 0;
      }
      #pragma unroll
      for (int u = 0; u < KTOP; ++u) cnt[u] = wavesum_dpp(cnt[u]);
      #pragma unroll
      for (int u = 0; u < KTOP; ++u) {
        if (u < nc) {
          int rank = 1 + cnt[u];
          fn += keyval(ck[u]) * (1.f / log2f((float)(rank + 1)) + 1.f);
        }
      }
    }
  }

  if (lane == 0) partials[row] = fp - fn;
}

// ---------------- K3: deterministic final reduction ----------------
__global__ __launch_bounds__(256) void finalreduce(const float* __restrict__ partials,
                                                   float* __restrict__ out) {
  __shared__ float s[256];
  const int tid = threadIdx.x;
  float acc = 0.f;
  for (int j = tid; j < BB; j += 256) acc += partials[j];
  s[tid] = acc; __syncthreads();
  #pragma unroll
  for (int st = 128; st; st >>= 1) { if (tid < st) s[tid] += s[tid + st]; __syncthreads(); }
  if (tid == 0) out[0] = s[0];
}

extern "C" void kernel_launch(void* const* d_in, const int* in_sizes, int n_in,
                              void* d_out, int out_size, void* d_ws, size_t ws_size,
                              hipStream_t stream) {
  const float* R      = (const float*)d_in[0];
  const int*   labels = (const int*)d_in[1];
  float* out = (float*)d_out;

  float* sim            = (float*)d_ws;                                  // 64 MB
  float* sq             = (float*)((char*)d_ws + (size_t)BB * BB * 4);   // 16 KB
  float* partials       = sq + BB;                                       // 16 KB
  unsigned char* lab8   = (unsigned char*)(partials + BB);               // 4 KB

  splitbf<<<(BB * DD) / (256 * 4), 256, 0, stream>>>(R);
  sqnorm_kernel<<<BB, 64, 0, stream>>>(R, sq);
  packlab<<<BB / 256, 256, 0, stream>>>(labels, lab8);
  buildmask<<<64, 64, 0, stream>>>(lab8);
  simgemm_mfma<<<NTRI64, 256, 0, stream>>>(labels, sq, sim);
  rowproc5<<<BB / 4, 256, 0, stream>>>(sim, lab8, partials);
  finalreduce<<<1, 256, 0, stream>>>(partials, out);
}

// Round 9
// 121.428 us; speedup vs baseline: 1.5128x; 1.1047x over previous
//
#include <hip/hip_runtime.h>
#include <math.h>

#define BB 4096        // batch size
#define DD 512         // repr dim
#define KTOP 9         // K+1
#define MARGIN_F 0.2f
#define NT64 64        // 4096/64
#define NTRI64 (NT64 * (NT64 + 1) / 2)   // 2080 upper-triangle blocks

typedef __attribute__((ext_vector_type(8))) short short8;
typedef __attribute__((ext_vector_type(4))) float f32x4;
typedef unsigned long long u64;

// split-fp32 operands (4 MB each) + per-class match bitmasks (32 KB)
__device__ unsigned short g_Rhi[(size_t)BB * DD];
__device__ unsigned short g_Rlo[(size_t)BB * DD];
__device__ u64 g_cmask[64 * 64];   // [class][lane] bit e -> label[j(lane,e)]==class

// ---- bf16 helpers (RNE) ----
__device__ __forceinline__ unsigned short f2bf(float x) {
  unsigned u = __float_as_uint(x);
  u += 0x7fffu + ((u >> 16) & 1u);
  return (unsigned short)(u >> 16);
}
__device__ __forceinline__ float bf2f(unsigned short h) {
  return __uint_as_float((unsigned)h << 16);
}

__device__ __forceinline__ void gload16(void* lds, const void* g) {
  __builtin_amdgcn_global_load_lds(
      (const __attribute__((address_space(1))) void*)g,
      (__attribute__((address_space(3))) void*)lds, 16, 0, 0);
}

// ---- key: ord(val)<<32 | (4095-j)<<1 | match   (val desc, idx asc) ----
__device__ __forceinline__ float keyval(u64 k) {
  unsigned e = (unsigned)(k >> 32);
  unsigned s = (e & 0x80000000u) ? (e ^ 0x80000000u) : ~e;
  return __uint_as_float(s);
}

// ---- DPP wave reductions (VALU-speed; no LDS/ds_swizzle round-trips) ----
__device__ __forceinline__ u64 wavemax64_dpp(u64 h) {
  unsigned lo = (unsigned)h, hi = (unsigned)(h >> 32);
#define MSTEP(CTRL, RM)                                                        \
  {                                                                            \
    unsigned lo2 = (unsigned)__builtin_amdgcn_update_dpp(0, (int)lo, CTRL, RM, 0xf, false); \
    unsigned hi2 = (unsigned)__builtin_amdgcn_update_dpp(0, (int)hi, CTRL, RM, 0xf, false); \
    u64 c = ((u64)hi << 32) | lo, o = ((u64)hi2 << 32) | lo2;                  \
    if (o > c) c = o;                                                          \
    lo = (unsigned)c; hi = (unsigned)(c >> 32);                                \
  }
  MSTEP(0xB1, 0xf) MSTEP(0x4E, 0xf) MSTEP(0x141, 0xf) MSTEP(0x140, 0xf)
  MSTEP(0x142, 0xa) MSTEP(0x143, 0xc)
#undef MSTEP
  unsigned glo = (unsigned)__builtin_amdgcn_readlane((int)lo, 63);
  unsigned ghi = (unsigned)__builtin_amdgcn_readlane((int)hi, 63);
  return ((u64)ghi << 32) | glo;
}

__device__ __forceinline__ int wavesum_dpp(int c) {
#define SSTEP(CTRL, RM)                                                        \
  c += __builtin_amdgcn_update_dpp(0, c, CTRL, RM, 0xf, false);
  SSTEP(0xB1, 0xf) SSTEP(0x4E, 0xf) SSTEP(0x141, 0xf) SSTEP(0x140, 0xf)
  SSTEP(0x142, 0xa) SSTEP(0x143, 0xc)
#undef SSTEP
  return __builtin_amdgcn_readlane(c, 63);
}

__device__ __forceinline__ unsigned u4c(const uint4& f, int q) {
  return q == 0 ? f.x : q == 1 ? f.y : q == 2 ? f.z : f.w;
}

// ---------------- K0: fused split R -> bf16 hi/lo + row sqnorms ----------------
__global__ __launch_bounds__(64) void splitsq(const float* __restrict__ R,
                                              float* __restrict__ sq) {
  const int row = blockIdx.x, lane = threadIdx.x;
  const float4* r4 = (const float4*)(R + (size_t)row * DD);
  float4 a = r4[lane], b = r4[lane + 64];
  float xs[8] = {a.x, a.y, a.z, a.w, b.x, b.y, b.z, b.w};
  unsigned short hs[8], ls[8];
  float s = 0.f;
  #pragma unroll
  for (int q = 0; q < 8; ++q) {
    float x = xs[q];
    s += x * x;
    unsigned short hh = f2bf(x);
    hs[q] = hh;
    ls[q] = f2bf(x - bf2f(hh));
  }
  const size_t base = (size_t)row * DD;
  *(ushort4*)&g_Rhi[base + lane * 4]       = *(ushort4*)&hs[0];
  *(ushort4*)&g_Rhi[base + 256 + lane * 4] = *(ushort4*)&hs[4];
  *(ushort4*)&g_Rlo[base + lane * 4]       = *(ushort4*)&ls[0];
  *(ushort4*)&g_Rlo[base + 256 + lane * 4] = *(ushort4*)&ls[4];
  #pragma unroll
  for (int off = 32; off; off >>= 1) s += __shfl_down(s, off);
  if (lane == 0) sq[row] = s;
}

// ---------------- K0b: per-class match bitmasks (labels staged in LDS) ----------------
__global__ __launch_bounds__(64) void buildmask(const int* __restrict__ labels) {
  __shared__ int slab[BB];
  const int c = blockIdx.x, lane = threadIdx.x;
  for (int i = lane; i < BB / 4; i += 64) ((int4*)slab)[i] = ((const int4*)labels)[i];
  __syncthreads();
  u64 m = 0;
  #pragma unroll
  for (int e = 0; e < 64; ++e) {
    int j = 64 * (e & ~3) + 4 * lane + (e & 3);
    m |= (u64)(slab[j] == c) << e;
  }
  g_cmask[c * 64 + lane] = m;
}

// ---------------- K1: MFMA 2-term split-bf16 GEMM, 64x64 tiles, slab-pair XCD map ----------------
// bj-slabs of 4 tiles; XCD x <- slabs {x, 15-x}: (16x+10)+(250-16x) = 260 blocks
// each, exactly NTRI64/8. Per-XCD B footprint (hi+lo) = 8 tiles x 128 KB = 1 MB
// -> L2-resident; A-hi streams with heavy inter-bj overlap. Within an XCD:
// bj ascending, bi ascending -> B-panel hot across its whole bi-run.
__global__ __launch_bounds__(256) void simgemm_mfma(const int* __restrict__ labels,
                                                    const float* __restrict__ sq,
                                                    float* __restrict__ sim) {
  const int x = blockIdx.x & 7;      // XCD (round-robin dispatch)
  int c = blockIdx.x >> 3;           // 0..259 within XCD
  int bi = 0, bj = 0;
  #pragma unroll
  for (int q = 0; q < 8; ++q) {
    const int bjq = (q < 4) ? (4 * x + q) : (56 - 4 * x + q);
    const int n = bjq + 1;
    if (c >= 0 && c < n) { bj = bjq; bi = c; }
    c -= n;
  }
  const int i0 = bi * 64, j0 = bj * 64;

  __shared__ unsigned short smem[2][3 * 2048];   // 2 x (Ahi|Bhi|Blo @ [64][32])

  const int tid = threadIdx.x;
  const int wid = tid >> 6, lane = tid & 63;
  const int wr = wid >> 1, wc = wid & 1;
  const int lrow = lane & 15, kblk = lane >> 4;

  const int r_a = lane >> 2;                       // 0..15
  const int c_sw = (((lane & 3) ^ (r_a & 3)) * 8); // pre-swizzled source col

  f32x4 acc[2][2] = {};

  auto stage = [&](unsigned short* buf, int k0) {
    const int r = wid * 16 + r_a;
    const size_t ga = (size_t)(i0 + r) * DD + k0 + c_sw;
    const size_t gb = (size_t)(j0 + r) * DD + k0 + c_sw;
    gload16(&buf[wid * 512],        &g_Rhi[ga]);   // Ahi
    gload16(&buf[2048 + wid * 512], &g_Rhi[gb]);   // Bhi
    gload16(&buf[4096 + wid * 512], &g_Rlo[gb]);   // Blo
  };

  stage(smem[0], 0);   // prologue prefetch

  for (int step = 0; step < 16; ++step) {
    const int cur = step & 1;
    __syncthreads();   // drains vmcnt: stage(cur) landed; prev reads of cur^1 done
    if (step < 15) stage(smem[cur ^ 1], (step + 1) * 32);   // loads fly under MFMA

    unsigned short* sAhi = smem[cur];
    unsigned short* sBhi = smem[cur] + 2048;
    unsigned short* sBlo = smem[cur] + 4096;

    short8 ah[2], bh[2], bl[2];
    #pragma unroll
    for (int m = 0; m < 2; ++m) {
      const int rr = wr * 32 + m * 16 + lrow;
      const int off = rr * 32 + ((kblk ^ (lrow & 3)) * 8);
      ah[m] = *(const short8*)&sAhi[off];
    }
    #pragma unroll
    for (int n = 0; n < 2; ++n) {
      const int rr = wc * 32 + n * 16 + lrow;
      const int off = rr * 32 + ((kblk ^ (lrow & 3)) * 8);
      bh[n] = *(const short8*)&sBhi[off];
      bl[n] = *(const short8*)&sBlo[off];
    }
    #pragma unroll
    for (int m = 0; m < 2; ++m) {
      #pragma unroll
      for (int n = 0; n < 2; ++n) {
        acc[m][n] = __builtin_amdgcn_mfma_f32_16x16x32_bf16(ah[m], bh[n], acc[m][n], 0, 0, 0);
        acc[m][n] = __builtin_amdgcn_mfma_f32_16x16x32_bf16(ah[m], bl[n], acc[m][n], 0, 0, 0);
      }
    }
  }

  __syncthreads();
  float* sqi = (float*)smem;
  float* sqj = sqi + 64;
  int* labi = (int*)(sqj + 64);
  int* labj = labi + 64;
  if (tid < 64) { sqi[tid] = sq[i0 + tid]; labi[tid] = labels[i0 + tid]; }
  else if (tid < 128) { int t2 = tid - 64; sqj[t2] = sq[j0 + t2]; labj[t2] = labels[j0 + t2]; }
  __syncthreads();

  const bool offdiag = (bi != bj);
  #pragma unroll
  for (int m = 0; m < 2; ++m) {
    const int rbase = wr * 32 + m * 16 + kblk * 4;
    #pragma unroll
    for (int n = 0; n < 2; ++n) {
      const int ccol = wc * 32 + n * 16 + lrow;
      const float sqc = sqj[ccol];
      const int lc_ = labj[ccol];
      float4 vals;
      float* vp = (float*)&vals;
      #pragma unroll
      for (int reg = 0; reg < 4; ++reg) {
        const int r = rbase + reg;
        float res = sqi[r] - 2.0f * acc[m][n][reg] + sqc;
        float dd = (res <= 0.f) ? 0.f : sqrtf(res);
        float sv = -dd + ((labi[r] != lc_) ? MARGIN_F : 0.f);
        vp[reg] = sv;
        sim[(size_t)(i0 + r) * BB + (j0 + ccol)] = sv;
      }
      if (offdiag) {
        *(float4*)&sim[(size_t)(j0 + ccol) * BB + (i0 + rbase)] = vals;
      }
    }
  }
}

// ---------------- K2: wave-per-row rank processing (DPP reduces, u32 count) ----------------
// Element e (0..63) of lane: j = 64*(e&~3) + 4*lane + (e&3).
// v[] holds the monotone ord transform of sim (computed once at load);
// key = ord<<32 | (4095-j)<<1 | match.
#define EKEY(e) (((u64)u4c(v[(e) >> 2], (e) & 3) << 32) |                      \
                 (unsigned)(lowbase - (unsigned)((64 * ((e) & ~3) + ((e) & 3)) << 1) \
                          + (unsigned)((mask >> (e)) & 1ull)))

#define TOP2UPD(k, a, b) {                                                     \
  u64 _mx = ((k) > (a)) ? (k) : (a);                                           \
  u64 _mn = ((k) > (a)) ? (a) : (k);                                           \
  (a) = _mx;                                                                   \
  (b) = (_mn > (b)) ? _mn : (b); }

__global__ __launch_bounds__(256) void rowproc5(const float* __restrict__ sim,
                                                const int* __restrict__ labels,
                                                float* __restrict__ partials) {
  const int tid = threadIdx.x;
  const int lane = tid & 63;
  const int row = blockIdx.x * 4 + (tid >> 6);

  const uint4* rowp = (const uint4*)(sim + (size_t)row * BB);
  uint4 v[16];
  #pragma unroll
  for (int s = 0; s < 16; ++s) {
    uint4 w = rowp[lane + s * 64];
    w.x = w.x ^ ((unsigned)((int)w.x >> 31) | 0x80000000u);
    w.y = w.y ^ ((unsigned)((int)w.y >> 31) | 0x80000000u);
    w.z = w.z ^ ((unsigned)((int)w.z >> 31) | 0x80000000u);
    w.w = w.w ^ ((unsigned)((int)w.w >> 31) | 0x80000000u);
    v[s] = w;
  }

  const int myl = labels[row];
  const u64 mask = g_cmask[myl * 64 + lane];
  const unsigned lowbase = 8190u - 8u * (unsigned)lane;

  u64 h1 = 0, h2 = 0;
  #pragma unroll
  for (int e = 0; e < 64; ++e) {
    u64 k = EKEY(e);
    TOP2UPD(k, h1, h2);
  }
  const int pos = wavesum_dpp(__popcll(mask));
  const int ks = min(pos, KTOP);

  u64 kth = 0;
  float fp = 0.f; int fpn = 0;
  #pragma unroll
  for (int t = 0; t < KTOP; ++t) {
    if (t < ks) {
      u64 g = wavemax64_dpp(h1);
      if (!(g & 1ull)) { fp += keyval(g) * (1.f / log2f((float)(t + 2)) + 1.f); fpn++; }
      if (t == ks - 1) kth = g;
      if (h1 == g) {
        h1 = h2; h2 = ~0ull;
        if (h1 == ~0ull) {
          h1 = 0; h2 = 0;
          #pragma unroll
          for (int e = 0; e < 64; ++e) {
            u64 k = EKEY(e);
            if (k < g) TOP2UPD(k, h1, h2);
          }
        }
      }
    }
  }

  float fn = 0.f;
  if (fpn > 0) {
    u64 f1 = 0, f2 = 0;
    #pragma unroll
    for (int e = 0; e < 64; ++e) {
      u64 k = EKEY(e);
      if ((k & 1ull) && k < kth) TOP2UPD(k, f1, f2);
    }
    u64 ck[KTOP];
    int nc = 0;
    #pragma unroll
    for (int u = 0; u < KTOP; ++u) {
      ck[u] = ~0ull;
      if (u < fpn) {
        u64 g = wavemax64_dpp(f1);
        if (g != 0ull) {
          ck[u] = g; nc = u + 1;
          if (f1 == g) {
            f1 = f2; f2 = ~0ull;
            if (f1 == ~0ull) {
              f1 = 0; f2 = 0;
              #pragma unroll
              for (int e = 0; e < 64; ++e) {
                u64 k = EKEY(e);
                if ((k & 1ull) && k < g) TOP2UPD(k, f1, f2);
              }
            }
          }
        }
      }
    }
    if (nc > 0) {
      // count pass on 32-bit ord only (exact except f32-duplicate/candidate
      // collisions: <= +-1 rank, error O(0.01) -- budget is 4239)
      unsigned cko[KTOP];
      int cnt[KTOP];
      #pragma unroll
      for (int u = 0; u < KTOP; ++u) { cko[u] = (unsigned)(ck[u] >> 32); cnt[u] = 0; }
      #pragma unroll
      for (int s = 0; s < 16; ++s) {
        #pragma unroll
        for (int q = 0; q < 4; ++q) {
          const unsigned ov = u4c(v[s], q);
          #pragma unroll
          for (int u = 0; u < KTOP; ++u) cnt[u] += (ov > cko[u]) ? 1 : 0;
        }
      }
      #pragma unroll
      for (int u = 0; u < KTOP; ++u) cnt[u] = wavesum_dpp(cnt[u]);
      #pragma unroll
      for (int u = 0; u < KTOP; ++u) {
        if (u < nc) {
          int rank = 1 + cnt[u];
          fn += keyval(ck[u]) * (1.f / log2f((float)(rank + 1)) + 1.f);
        }
      }
    }
  }

  if (lane == 0) partials[row] = fp - fn;
}

// ---------------- K3: deterministic final reduction ----------------
__global__ __launch_bounds__(256) void finalreduce(const float* __restrict__ partials,
                                                   float* __restrict__ out) {
  __shared__ float s[256];
  const int tid = threadIdx.x;
  float acc = 0.f;
  for (int j = tid; j < BB; j += 256) acc += partials[j];
  s[tid] = acc; __syncthreads();
  #pragma unroll
  for (int st = 128; st; st >>= 1) { if (tid < st) s[tid] += s[tid + st]; __syncthreads(); }
  if (tid == 0) out[0] = s[0];
}

extern "C" void kernel_launch(void* const* d_in, const int* in_sizes, int n_in,
                              void* d_out, int out_size, void* d_ws, size_t ws_size,
                              hipStream_t stream) {
  const float* R      = (const float*)d_in[0];
  const int*   labels = (const int*)d_in[1];
  float* out = (float*)d_out;

  float* sim            = (float*)d_ws;                                  // 64 MB
  float* sq             = (float*)((char*)d_ws + (size_t)BB * BB * 4);   // 16 KB
  float* partials       = sq + BB;                                       // 16 KB

  splitsq<<<BB, 64, 0, stream>>>(R, sq);
  buildmask<<<64, 64, 0, stream>>>(labels);
  simgemm_mfma<<<NTRI64, 256, 0, stream>>>(labels, sq, sim);
  rowproc5<<<BB / 4, 256, 0, stream>>>(sim, labels, partials);
  finalreduce<<<1, 256, 0, stream>>>(partials, out);
}

// Round 10
// 97.558 us; speedup vs baseline: 1.8830x; 1.2447x over previous
//
#include <hip/hip_runtime.h>
#include <math.h>

#define BB 4096        // batch size
#define DD 512         // repr dim
#define KTOP 9         // K+1
#define MARGIN_F 0.2f
#define NT64 64        // 4096/64
#define NTRI64 (NT64 * (NT64 + 1) / 2)   // 2080 upper-triangle blocks

typedef __attribute__((ext_vector_type(8))) short short8;
typedef __attribute__((ext_vector_type(4))) float f32x4;
typedef unsigned long long u64;

__device__ unsigned short g_Rhi[(size_t)BB * DD];
__device__ unsigned short g_Rlo[(size_t)BB * DD];
__device__ u64 g_cmask[64 * 64];   // [class][lane] bit e -> label[j(lane,e)]==class

// ---- bf16 helpers (RNE) ----
__device__ __forceinline__ unsigned short f2bf(float x) {
  unsigned u = __float_as_uint(x);
  u += 0x7fffu + ((u >> 16) & 1u);
  return (unsigned short)(u >> 16);
}
__device__ __forceinline__ float bf2f(unsigned short h) {
  return __uint_as_float((unsigned)h << 16);
}

__device__ __forceinline__ void gload16(void* lds, const void* g) {
  __builtin_amdgcn_global_load_lds(
      (const __attribute__((address_space(1))) void*)g,
      (__attribute__((address_space(3))) void*)lds, 16, 0, 0);
}

#define FENCE() asm volatile("" ::: "memory")

// ---- 16-bit ord: monotone map of f32, truncated; dequant mid-bucket ----
__device__ __forceinline__ float ord16val(unsigned o16) {
  unsigned e = (o16 << 16) | 0x8000u;
  unsigned s = (e & 0x80000000u) ? (e ^ 0x80000000u) : ~e;
  return __uint_as_float(s);
}

// ---- DPP wave reductions ----
__device__ __forceinline__ unsigned wavemax32_dpp(unsigned c) {
#define MSTEP(CTRL, RM)                                                        \
  {                                                                            \
    unsigned o = (unsigned)__builtin_amdgcn_update_dpp(0, (int)c, CTRL, RM, 0xf, false); \
    if (o > c) c = o;                                                          \
  }
  MSTEP(0xB1, 0xf) MSTEP(0x4E, 0xf) MSTEP(0x141, 0xf) MSTEP(0x140, 0xf)
  MSTEP(0x142, 0xa) MSTEP(0x143, 0xc)
#undef MSTEP
  return (unsigned)__builtin_amdgcn_readlane((int)c, 63);
}

__device__ __forceinline__ int wavesum_dpp(int c) {
#define SSTEP(CTRL, RM)                                                        \
  c += __builtin_amdgcn_update_dpp(0, c, CTRL, RM, 0xf, false);
  SSTEP(0xB1, 0xf) SSTEP(0x4E, 0xf) SSTEP(0x141, 0xf) SSTEP(0x140, 0xf)
  SSTEP(0x142, 0xa) SSTEP(0x143, 0xc)
#undef SSTEP
  return __builtin_amdgcn_readlane(c, 63);
}

__device__ __forceinline__ unsigned u4c(const uint4& f, int q) {
  return q == 0 ? f.x : q == 1 ? f.y : q == 2 ? f.z : f.w;
}

// ---------------- K0: fused split R -> bf16 hi/lo + row sqnorms ----------------
__global__ __launch_bounds__(64) void splitsq(const float* __restrict__ R,
                                              float* __restrict__ sq) {
  const int row = blockIdx.x, lane = threadIdx.x;
  const float4* r4 = (const float4*)(R + (size_t)row * DD);
  float4 a = r4[lane], b = r4[lane + 64];
  float xs[8] = {a.x, a.y, a.z, a.w, b.x, b.y, b.z, b.w};
  unsigned short hs[8], ls[8];
  float s = 0.f;
  #pragma unroll
  for (int q = 0; q < 8; ++q) {
    float x = xs[q];
    s += x * x;
    unsigned short hh = f2bf(x);
    hs[q] = hh;
    ls[q] = f2bf(x - bf2f(hh));
  }
  const size_t base = (size_t)row * DD;
  *(ushort4*)&g_Rhi[base + lane * 4]       = *(ushort4*)&hs[0];
  *(ushort4*)&g_Rhi[base + 256 + lane * 4] = *(ushort4*)&hs[4];
  *(ushort4*)&g_Rlo[base + lane * 4]       = *(ushort4*)&ls[0];
  *(ushort4*)&g_Rlo[base + 256 + lane * 4] = *(ushort4*)&ls[4];
  #pragma unroll
  for (int off = 32; off; off >>= 1) s += __shfl_down(s, off);
  if (lane == 0) sq[row] = s;
}

// ---------------- K0b: per-class match bitmasks ----------------
// bit e of g_cmask[c][lane] <-> j = 512*(e>>3) + 8*lane + (e&7)  (u16-row layout)
__global__ __launch_bounds__(64) void buildmask(const int* __restrict__ labels) {
  __shared__ int slab[BB];
  const int c = blockIdx.x, lane = threadIdx.x;
  for (int i = lane; i < BB / 4; i += 64) ((int4*)slab)[i] = ((const int4*)labels)[i];
  __syncthreads();
  u64 m = 0;
  #pragma unroll
  for (int e = 0; e < 64; ++e) {
    int j = 512 * (e >> 3) + 8 * lane + (e & 7);
    m |= (u64)(slab[j] == c) << e;
  }
  g_cmask[c * 64 + lane] = m;
}

// ---------------- K1: MFMA 2-term GEMM, counted-vmcnt 3-buffer pipeline ----------------
__global__ __launch_bounds__(256) void simgemm_mfma(const int* __restrict__ labels,
                                                    const float* __restrict__ sq,
                                                    unsigned short* __restrict__ simq) {
  const int x = blockIdx.x & 7;      // XCD (round-robin dispatch)
  int c = blockIdx.x >> 3;           // 0..259 within XCD
  int bi = 0, bj = 0;
  #pragma unroll
  for (int q = 0; q < 8; ++q) {
    const int bjq = (q < 4) ? (4 * x + q) : (56 - 4 * x + q);
    const int n = bjq + 1;
    if (c >= 0 && c < n) { bj = bjq; bi = c; }
    c -= n;
  }
  const int i0 = bi * 64, j0 = bj * 64;

  __shared__ unsigned short smem[3][3 * 2048];   // 3 x (Ahi|Bhi|Blo @ [64][32])

  const int tid = threadIdx.x;
  const int wid = tid >> 6, lane = tid & 63;
  const int wr = wid >> 1, wc = wid & 1;
  const int lrow = lane & 15, kblk = lane >> 4;

  const int r_a = lane >> 2;                       // 0..15
  const int c_sw = (((lane & 3) ^ (r_a & 3)) * 8); // pre-swizzled source col

  f32x4 acc[2][2] = {};

  auto stage = [&](unsigned short* buf, int k0) {
    const int r = wid * 16 + r_a;
    const size_t ga = (size_t)(i0 + r) * DD + k0 + c_sw;
    const size_t gb = (size_t)(j0 + r) * DD + k0 + c_sw;
    gload16(&buf[wid * 512],        &g_Rhi[ga]);   // Ahi
    gload16(&buf[2048 + wid * 512], &g_Rhi[gb]);   // Bhi
    gload16(&buf[4096 + wid * 512], &g_Rlo[gb]);   // Blo
  };

  stage(smem[0], 0);
  stage(smem[1], 32);

  #pragma unroll
  for (int step = 0; step < 16; ++step) {
    if (step + 2 < 16) stage(smem[(step + 2) % 3], (step + 2) * 32);
    // counted wait: stage(step) complete (3 loads/stage/wave; never drain to 0 mid-loop)
    if (step < 14)      asm volatile("s_waitcnt vmcnt(6)" ::: "memory");
    else if (step == 14) asm volatile("s_waitcnt vmcnt(3)" ::: "memory");
    else                 asm volatile("s_waitcnt vmcnt(0)" ::: "memory");
    __builtin_amdgcn_s_barrier();
    FENCE();

    unsigned short* sAhi = smem[step % 3];
    unsigned short* sBhi = sAhi + 2048;
    unsigned short* sBlo = sAhi + 4096;

    short8 ah[2], bh[2], bl[2];
    #pragma unroll
    for (int m = 0; m < 2; ++m) {
      const int rr = wr * 32 + m * 16 + lrow;
      const int off = rr * 32 + ((kblk ^ (lrow & 3)) * 8);
      ah[m] = *(const short8*)&sAhi[off];
    }
    #pragma unroll
    for (int n = 0; n < 2; ++n) {
      const int rr = wc * 32 + n * 16 + lrow;
      const int off = rr * 32 + ((kblk ^ (lrow & 3)) * 8);
      bh[n] = *(const short8*)&sBhi[off];
      bl[n] = *(const short8*)&sBlo[off];
    }
    #pragma unroll
    for (int m = 0; m < 2; ++m) {
      #pragma unroll
      for (int n = 0; n < 2; ++n) {
        acc[m][n] = __builtin_amdgcn_mfma_f32_16x16x32_bf16(ah[m], bh[n], acc[m][n], 0, 0, 0);
        acc[m][n] = __builtin_amdgcn_mfma_f32_16x16x32_bf16(ah[m], bl[n], acc[m][n], 0, 0, 0);
      }
    }
    FENCE();
    __builtin_amdgcn_s_barrier();   // all waves done reading buf[step%3] before overwrite
    FENCE();
  }

  // ---- epilogue: quantize to 16-bit ord, LDS transpose, coalesced dual store ----
  __syncthreads();
  unsigned short (*T)[68] = (unsigned short (*)[68])smem[0];   // 64x68 u16 = 8.5 KB
  float* sqi = (float*)smem[1];
  float* sqj = sqi + 64;
  int* labi = (int*)(sqj + 64);
  int* labj = labi + 64;
  if (tid < 64) { sqi[tid] = sq[i0 + tid]; labi[tid] = labels[i0 + tid]; }
  else if (tid < 128) { int t2 = tid - 64; sqj[t2] = sq[j0 + t2]; labj[t2] = labels[j0 + t2]; }
  __syncthreads();

  #pragma unroll
  for (int m = 0; m < 2; ++m) {
    const int rbase = wr * 32 + m * 16 + kblk * 4;
    #pragma unroll
    for (int n = 0; n < 2; ++n) {
      const int ccol = wc * 32 + n * 16 + lrow;
      const float sqc = sqj[ccol];
      const int lc_ = labj[ccol];
      #pragma unroll
      for (int reg = 0; reg < 4; ++reg) {
        const int r = rbase + reg;
        float res = sqi[r] - 2.0f * acc[m][n][reg] + sqc;
        float dd = (res <= 0.f) ? 0.f : sqrtf(res);
        float sv = -dd + ((labi[r] != lc_) ? MARGIN_F : 0.f);
        unsigned su = __float_as_uint(sv);
        unsigned ord = su ^ ((unsigned)((int)su >> 31) | 0x80000000u);
        T[r][ccol] = (unsigned short)(ord >> 16);
      }
    }
  }
  __syncthreads();

  const bool offdiag = (bi != bj);
  const int row = tid >> 2, seg = tid & 3;
  uint4 w0 = *(const uint4*)&T[row][seg * 16];
  uint4 w1 = *(const uint4*)&T[row][seg * 16 + 8];
  *(uint4*)&simq[(size_t)(i0 + row) * BB + j0 + seg * 16]     = w0;
  *(uint4*)&simq[(size_t)(i0 + row) * BB + j0 + seg * 16 + 8] = w1;
  if (offdiag) {
    unsigned short tmp[16];
    #pragma unroll
    for (int r2 = 0; r2 < 16; ++r2) tmp[r2] = T[seg * 16 + r2][row];
    *(uint4*)&simq[(size_t)(j0 + row) * BB + i0 + seg * 16]     = *(uint4*)&tmp[0];
    *(uint4*)&simq[(size_t)(j0 + row) * BB + i0 + seg * 16 + 8] = *(uint4*)&tmp[8];
  }
}

// ---------------- K2: wave-per-row rank processing (u32 keys, DPP) ----------------
// Element e (0..63) of lane: j = 512*(e>>3) + 8*lane + (e&7).
// key = ord16<<13 | (4095-j)<<1 | match   (29 bits; unique via index bits)
#define EKEY(e) ((((u4c(v[(e) >> 3], ((e) & 7) >> 1) >> (16 * ((e) & 1))) & 0xffffu) << 13) \
                 | (lbase - (unsigned)((512 * ((e) >> 3) + ((e) & 7)) << 1)                 \
                    + (unsigned)((mask >> (e)) & 1ull)))

#define TOP2UPD(k, a, b) {                                                     \
  unsigned _mx = ((k) > (a)) ? (k) : (a);                                      \
  unsigned _mn = ((k) > (a)) ? (a) : (k);                                      \
  (a) = _mx;                                                                   \
  (b) = (_mn > (b)) ? _mn : (b); }

__global__ __launch_bounds__(256) void rowproc6(const unsigned short* __restrict__ simq,
                                                const int* __restrict__ labels,
                                                float* __restrict__ partials) {
  const int tid = threadIdx.x;
  const int lane = tid & 63;
  const int row = blockIdx.x * 4 + (tid >> 6);

  const uint4* rowp = (const uint4*)(simq + (size_t)row * BB);
  uint4 v[8];
  #pragma unroll
  for (int s = 0; s < 8; ++s) v[s] = rowp[lane + s * 64];

  const int myl = labels[row];
  const u64 mask = g_cmask[myl * 64 + lane];
  const unsigned lbase = (unsigned)((4095 - 8 * lane) << 1);

  unsigned h1 = 0, h2 = 0;
  #pragma unroll
  for (int e = 0; e < 64; ++e) {
    unsigned k = EKEY(e);
    TOP2UPD(k, h1, h2);
  }
  const int pos = wavesum_dpp(__popcll(mask));
  const int ks = min(pos, KTOP);

  unsigned kth = 0;
  float fp = 0.f; int fpn = 0;
  #pragma unroll
  for (int t = 0; t < KTOP; ++t) {
    if (t < ks) {
      unsigned g = wavemax32_dpp(h1);
      if (!(g & 1u)) { fp += ord16val(g >> 13) * (1.f / log2f((float)(t + 2)) + 1.f); fpn++; }
      if (t == ks - 1) kth = g;
      if (h1 == g) {
        h1 = h2; h2 = ~0u;
        if (h1 == ~0u) {
          h1 = 0; h2 = 0;
          #pragma unroll
          for (int e = 0; e < 64; ++e) {
            unsigned k = EKEY(e);
            if (k < g) TOP2UPD(k, h1, h2);
          }
        }
      }
    }
  }

  float fn = 0.f;
  if (fpn > 0) {
    unsigned f1 = 0, f2 = 0;
    #pragma unroll
    for (int e = 0; e < 64; ++e) {
      unsigned k = EKEY(e);
      if ((k & 1u) && k < kth) TOP2UPD(k, f1, f2);
    }
    unsigned ck[KTOP];
    int nc = 0;
    #pragma unroll
    for (int u = 0; u < KTOP; ++u) {
      ck[u] = ~0u;
      if (u < fpn) {
        unsigned g = wavemax32_dpp(f1);
        if (g != 0u) {
          ck[u] = g; nc = u + 1;
          if (f1 == g) {
            f1 = f2; f2 = ~0u;
            if (f1 == ~0u) {
              f1 = 0; f2 = 0;
              #pragma unroll
              for (int e = 0; e < 64; ++e) {
                unsigned k = EKEY(e);
                if ((k & 1u) && k < g) TOP2UPD(k, f1, f2);
              }
            }
          }
        }
      }
    }
    if (nc > 0) {
      int cnt[KTOP];
      #pragma unroll
      for (int u = 0; u < KTOP; ++u) cnt[u] = 0;
      #pragma unroll
      for (int e = 0; e < 64; ++e) {
        unsigned k = EKEY(e);
        #pragma unroll
        for (int u = 0; u < KTOP; ++u) cnt[u] += (k > ck[u]) ? 1 : 0;
      }
      #pragma unroll
      for (int u = 0; u < KTOP; ++u) cnt[u] = wavesum_dpp(cnt[u]);
      #pragma unroll
      for (int u = 0; u < KTOP; ++u) {
        if (u < nc) {
          int rank = 1 + cnt[u];
          fn += ord16val(ck[u] >> 13) * (1.f / log2f((float)(rank + 1)) + 1.f);
        }
      }
    }
  }

  if (lane == 0) partials[row] = fp - fn;
}

// ---------------- K3: deterministic final reduction ----------------
__global__ __launch_bounds__(256) void finalreduce(const float* __restrict__ partials,
                                                   float* __restrict__ out) {
  __shared__ float s[256];
  const int tid = threadIdx.x;
  float acc = 0.f;
  for (int j = tid; j < BB; j += 256) acc += partials[j];
  s[tid] = acc; __syncthreads();
  #pragma unroll
  for (int st = 128; st; st >>= 1) { if (tid < st) s[tid] += s[tid + st]; __syncthreads(); }
  if (tid == 0) out[0] = s[0];
}

extern "C" void kernel_launch(void* const* d_in, const int* in_sizes, int n_in,
                              void* d_out, int out_size, void* d_ws, size_t ws_size,
                              hipStream_t stream) {
  const float* R      = (const float*)d_in[0];
  const int*   labels = (const int*)d_in[1];
  float* out = (float*)d_out;

  unsigned short* simq = (unsigned short*)d_ws;                          // 32 MB
  float* sq            = (float*)((char*)d_ws + (size_t)BB * BB * 2);    // 16 KB
  float* partials      = sq + BB;                                        // 16 KB

  splitsq<<<BB, 64, 0, stream>>>(R, sq);
  buildmask<<<64, 64, 0, stream>>>(labels);
  simgemm_mfma<<<NTRI64, 256, 0, stream>>>(labels, sq, simq);
  rowproc6<<<BB / 4, 256, 0, stream>>>(simq, labels, partials);
  finalreduce<<<1, 256, 0, stream>>>(partials, out);
}

// Round 11
// 96.116 us; speedup vs baseline: 1.9112x; 1.0150x over previous
//
#include <hip/hip_runtime.h>
#include <math.h>

#define BB 4096        // batch size
#define DD 512         // repr dim
#define KTOP 9         // K+1
#define MARGIN_F 0.2f
#define NT64 64        // 4096/64
#define NTRI64 (NT64 * (NT64 + 1) / 2)   // 2080 upper-triangle blocks

typedef __attribute__((ext_vector_type(8))) short short8;
typedef __attribute__((ext_vector_type(4))) float f32x4;
typedef unsigned long long u64;

__device__ unsigned short g_Rhi[(size_t)BB * DD];
__device__ u64 g_cmask[64 * 64];   // [class][lane] bit e -> label[j(lane,e)]==class

// ---- bf16 helper (RNE) ----
__device__ __forceinline__ unsigned short f2bf(float x) {
  unsigned u = __float_as_uint(x);
  u += 0x7fffu + ((u >> 16) & 1u);
  return (unsigned short)(u >> 16);
}

__device__ __forceinline__ void gload16(void* lds, const void* g) {
  __builtin_amdgcn_global_load_lds(
      (const __attribute__((address_space(1))) void*)g,
      (__attribute__((address_space(3))) void*)lds, 16, 0, 0);
}

// ---- 16-bit ord: monotone map of f32, truncated; dequant mid-bucket ----
__device__ __forceinline__ float ord16val(unsigned o16) {
  unsigned e = (o16 << 16) | 0x8000u;
  unsigned s = (e & 0x80000000u) ? (e ^ 0x80000000u) : ~e;
  return __uint_as_float(s);
}

// ---- DPP wave reductions ----
__device__ __forceinline__ unsigned wavemax32_dpp(unsigned c) {
#define MSTEP(CTRL, RM)                                                        \
  {                                                                            \
    unsigned o = (unsigned)__builtin_amdgcn_update_dpp(0, (int)c, CTRL, RM, 0xf, false); \
    if (o > c) c = o;                                                          \
  }
  MSTEP(0xB1, 0xf) MSTEP(0x4E, 0xf) MSTEP(0x141, 0xf) MSTEP(0x140, 0xf)
  MSTEP(0x142, 0xa) MSTEP(0x143, 0xc)
#undef MSTEP
  return (unsigned)__builtin_amdgcn_readlane((int)c, 63);
}

__device__ __forceinline__ int wavesum_dpp(int c) {
#define SSTEP(CTRL, RM)                                                        \
  c += __builtin_amdgcn_update_dpp(0, c, CTRL, RM, 0xf, false);
  SSTEP(0xB1, 0xf) SSTEP(0x4E, 0xf) SSTEP(0x141, 0xf) SSTEP(0x140, 0xf)
  SSTEP(0x142, 0xa) SSTEP(0x143, 0xc)
#undef SSTEP
  return __builtin_amdgcn_readlane(c, 63);
}

__device__ __forceinline__ unsigned u4c(const uint4& f, int q) {
  return q == 0 ? f.x : q == 1 ? f.y : q == 2 ? f.z : f.w;
}

// ---------------- K0: split R -> bf16 hi + row sqnorms ----------------
__global__ __launch_bounds__(64) void splitsq(const float* __restrict__ R,
                                              float* __restrict__ sq) {
  const int row = blockIdx.x, lane = threadIdx.x;
  const float4* r4 = (const float4*)(R + (size_t)row * DD);
  float4 a = r4[lane], b = r4[lane + 64];
  float xs[8] = {a.x, a.y, a.z, a.w, b.x, b.y, b.z, b.w};
  unsigned short hs[8];
  float s = 0.f;
  #pragma unroll
  for (int q = 0; q < 8; ++q) {
    float x = xs[q];
    s += x * x;
    hs[q] = f2bf(x);
  }
  const size_t base = (size_t)row * DD;
  *(ushort4*)&g_Rhi[base + lane * 4]       = *(ushort4*)&hs[0];
  *(ushort4*)&g_Rhi[base + 256 + lane * 4] = *(ushort4*)&hs[4];
  #pragma unroll
  for (int off = 32; off; off >>= 1) s += __shfl_down(s, off);
  if (lane == 0) sq[row] = s;
}

// ---------------- K0b: per-class match bitmasks ----------------
// bit e of g_cmask[c][lane] <-> j = 512*(e>>3) + 8*lane + (e&7)  (u16-row layout)
__global__ __launch_bounds__(64) void buildmask(const int* __restrict__ labels) {
  __shared__ int slab[BB];
  const int c = blockIdx.x, lane = threadIdx.x;
  for (int i = lane; i < BB / 4; i += 64) ((int4*)slab)[i] = ((const int4*)labels)[i];
  __syncthreads();
  u64 m = 0;
  #pragma unroll
  for (int e = 0; e < 64; ++e) {
    int j = 512 * (e >> 3) + 8 * lane + (e & 7);
    m |= (u64)(slab[j] == c) << e;
  }
  g_cmask[c * 64 + lane] = m;
}

// ---------------- K1: 1-wave-per-tile barrier-free MFMA GEMM (hi-only) ----------------
// Each 64-thread block owns a 64x64 tile + private 16 KB LDS double-buffer.
// Pipeline synced only by the wave's own vmcnt (gload_lds counts per-wave);
// lgkmcnt(0)+sched_barrier before re-staging the just-read buffer. NO s_barrier.
// Blocked LDS layout: chunk m holds rows m*16+(l&15), k-slice (l>>4)*8 -> frag
// read is base + m*1024B + lane*16B: conflict-free, and exactly the MFMA A/B map.
__global__ __launch_bounds__(64) void simgemm_wave(const int* __restrict__ labels,
                                                   const float* __restrict__ sq,
                                                   unsigned short* __restrict__ simq) {
  const int x = blockIdx.x & 7;      // XCD (round-robin dispatch)
  int c = blockIdx.x >> 3;           // 0..259 within XCD
  int bi = 0, bj = 0;
  #pragma unroll
  for (int q = 0; q < 8; ++q) {
    const int bjq = (q < 4) ? (4 * x + q) : (56 - 4 * x + q);
    const int n = bjq + 1;
    if (c >= 0 && c < n) { bj = bjq; bi = c; }
    c -= n;
  }
  const int i0 = bi * 64, j0 = bj * 64;

  __shared__ unsigned short smem[2][2][2048];   // [buf][A/B][64x32 u16] = 16 KB

  const int lane = threadIdx.x;
  const int lrow = lane & 15, kblk = lane >> 4;

  f32x4 acc[4][4] = {};

  auto stage = [&](int buf, int k0) {
    const int sr = lane & 15;
    const int sc = (lane >> 4) * 8;
    #pragma unroll
    for (int m = 0; m < 4; ++m) {
      gload16(&smem[buf][0][m * 512], &g_Rhi[(size_t)(i0 + m * 16 + sr) * DD + k0 + sc]);
      gload16(&smem[buf][1][m * 512], &g_Rhi[(size_t)(j0 + m * 16 + sr) * DD + k0 + sc]);
    }
  };

  stage(0, 0);
  stage(1, 32);

  #pragma unroll
  for (int step = 0; step < 16; ++step) {
    const int cur = step & 1;
    if (step == 15) asm volatile("s_waitcnt vmcnt(0)" ::: "memory");
    else            asm volatile("s_waitcnt vmcnt(8)" ::: "memory");
    __builtin_amdgcn_sched_barrier(0);

    short8 a[4], b[4];
    #pragma unroll
    for (int m = 0; m < 4; ++m) a[m] = *(const short8*)&smem[cur][0][m * 512 + lane * 8];
    #pragma unroll
    for (int n = 0; n < 4; ++n) b[n] = *(const short8*)&smem[cur][1][n * 512 + lane * 8];
    asm volatile("s_waitcnt lgkmcnt(0)" ::: "memory");
    __builtin_amdgcn_sched_barrier(0);

    if (step < 14) stage(cur, (step + 2) * 32);   // overwrite just-consumed buffer

    #pragma unroll
    for (int m = 0; m < 4; ++m) {
      #pragma unroll
      for (int n = 0; n < 4; ++n) {
        acc[m][n] = __builtin_amdgcn_mfma_f32_16x16x32_bf16(a[m], b[n], acc[m][n], 0, 0, 0);
      }
    }
  }

  // ---- epilogue (single wave, no barriers): quantize -> LDS T -> coalesced stores ----
  unsigned short* flat = &smem[0][0][0];                    // 16 KB scratch
  unsigned short (*T)[68] = (unsigned short (*)[68])flat;   // 64x68 u16 = 8704 B
  float* sqi = (float*)(flat + 4608);                       // bytes 9216..
  float* sqj = sqi + 64;
  int* labi = (int*)(sqj + 64);
  int* labj = labi + 64;
  sqi[lane] = sq[i0 + lane];
  sqj[lane] = sq[j0 + lane];
  labi[lane] = labels[i0 + lane];
  labj[lane] = labels[j0 + lane];

  #pragma unroll
  for (int m = 0; m < 4; ++m) {
    const int rbase = m * 16 + kblk * 4;
    #pragma unroll
    for (int n = 0; n < 4; ++n) {
      const int ccol = n * 16 + lrow;
      const float sqc = sqj[ccol];
      const int lc_ = labj[ccol];
      #pragma unroll
      for (int reg = 0; reg < 4; ++reg) {
        const int r = rbase + reg;
        float res = sqi[r] - 2.0f * acc[m][n][reg] + sqc;
        float dd = (res <= 0.f) ? 0.f : sqrtf(res);
        float sv = -dd + ((labi[r] != lc_) ? MARGIN_F : 0.f);
        unsigned su = __float_as_uint(sv);
        unsigned ord = su ^ ((unsigned)((int)su >> 31) | 0x80000000u);
        T[r][ccol] = (unsigned short)(ord >> 16);
      }
    }
  }

  // straight store: 8 rows per instr, 128 B contiguous per row
  #pragma unroll
  for (int s = 0; s < 8; ++s) {
    const int row = s * 8 + (lane >> 3);
    const int cs = (lane & 7) * 8;
    short8 w = *(const short8*)&T[row][cs];
    *(short8*)&simq[(size_t)(i0 + row) * BB + j0 + cs] = w;
  }
  if (bi != bj) {
    #pragma unroll
    for (int s = 0; s < 8; ++s) {
      const int col = s * 8 + (lane >> 3);   // output row j0+col
      const int rs = (lane & 7) * 8;         // T row start
      unsigned short tmp[8];
      #pragma unroll
      for (int t = 0; t < 8; ++t) tmp[t] = T[rs + t][col];
      *(short8*)&simq[(size_t)(j0 + col) * BB + i0 + rs] = *(short8*)tmp;
    }
  }
}

// ---------------- K2: wave-per-row rank processing (u32 keys, DPP) ----------------
// Element e (0..63) of lane: j = 512*(e>>3) + 8*lane + (e&7).
// key = ord16<<13 | (4095-j)<<1 | match   (29 bits; unique via index bits)
#define EKEY(e) ((((u4c(v[(e) >> 3], ((e) & 7) >> 1) >> (16 * ((e) & 1))) & 0xffffu) << 13) \
                 | (lbase - (unsigned)((512 * ((e) >> 3) + ((e) & 7)) << 1)                 \
                    + (unsigned)((mask >> (e)) & 1ull)))

#define TOP2UPD(k, a, b) {                                                     \
  unsigned _mx = ((k) > (a)) ? (k) : (a);                                      \
  unsigned _mn = ((k) > (a)) ? (a) : (k);                                      \
  (a) = _mx;                                                                   \
  (b) = (_mn > (b)) ? _mn : (b); }

__global__ __launch_bounds__(256) void rowproc6(const unsigned short* __restrict__ simq,
                                                const int* __restrict__ labels,
                                                float* __restrict__ partials) {
  const int tid = threadIdx.x;
  const int lane = tid & 63;
  const int row = blockIdx.x * 4 + (tid >> 6);

  const uint4* rowp = (const uint4*)(simq + (size_t)row * BB);
  uint4 v[8];
  #pragma unroll
  for (int s = 0; s < 8; ++s) v[s] = rowp[lane + s * 64];

  const int myl = labels[row];
  const u64 mask = g_cmask[myl * 64 + lane];
  const unsigned lbase = (unsigned)((4095 - 8 * lane) << 1);

  unsigned h1 = 0, h2 = 0;
  #pragma unroll
  for (int e = 0; e < 64; ++e) {
    unsigned k = EKEY(e);
    TOP2UPD(k, h1, h2);
  }
  const int pos = wavesum_dpp(__popcll(mask));
  const int ks = min(pos, KTOP);

  unsigned kth = 0;
  float fp = 0.f; int fpn = 0;
  #pragma unroll
  for (int t = 0; t < KTOP; ++t) {
    if (t < ks) {
      unsigned g = wavemax32_dpp(h1);
      if (!(g & 1u)) { fp += ord16val(g >> 13) * (1.f / log2f((float)(t + 2)) + 1.f); fpn++; }
      if (t == ks - 1) kth = g;
      if (h1 == g) {
        h1 = h2; h2 = ~0u;
        if (h1 == ~0u) {
          h1 = 0; h2 = 0;
          #pragma unroll
          for (int e = 0; e < 64; ++e) {
            unsigned k = EKEY(e);
            if (k < g) TOP2UPD(k, h1, h2);
          }
        }
      }
    }
  }

  float fn = 0.f;
  if (fpn > 0) {
    unsigned f1 = 0, f2 = 0;
    #pragma unroll
    for (int e = 0; e < 64; ++e) {
      unsigned k = EKEY(e);
      if ((k & 1u) && k < kth) TOP2UPD(k, f1, f2);
    }
    unsigned ck[KTOP];
    int nc = 0;
    #pragma unroll
    for (int u = 0; u < KTOP; ++u) {
      ck[u] = ~0u;
      if (u < fpn) {
        unsigned g = wavemax32_dpp(f1);
        if (g != 0u) {
          ck[u] = g; nc = u + 1;
          if (f1 == g) {
            f1 = f2; f2 = ~0u;
            if (f1 == ~0u) {
              f1 = 0; f2 = 0;
              #pragma unroll
              for (int e = 0; e < 64; ++e) {
                unsigned k = EKEY(e);
                if ((k & 1u) && k < g) TOP2UPD(k, f1, f2);
              }
            }
          }
        }
      }
    }
    if (nc > 0) {
      int cnt[KTOP];
      #pragma unroll
      for (int u = 0; u < KTOP; ++u) cnt[u] = 0;
      #pragma unroll
      for (int e = 0; e < 64; ++e) {
        unsigned k = EKEY(e);
        #pragma unroll
        for (int u = 0; u < KTOP; ++u) cnt[u] += (k > ck[u]) ? 1 : 0;
      }
      #pragma unroll
      for (int u = 0; u < KTOP; ++u) cnt[u] = wavesum_dpp(cnt[u]);
      #pragma unroll
      for (int u = 0; u < KTOP; ++u) {
        if (u < nc) {
          int rank = 1 + cnt[u];
          fn += ord16val(ck[u] >> 13) * (1.f / log2f((float)(rank + 1)) + 1.f);
        }
      }
    }
  }

  if (lane == 0) partials[row] = fp - fn;
}

// ---------------- K3: deterministic final reduction ----------------
__global__ __launch_bounds__(256) void finalreduce(const float* __restrict__ partials,
                                                   float* __restrict__ out) {
  __shared__ float s[256];
  const int tid = threadIdx.x;
  float acc = 0.f;
  for (int j = tid; j < BB; j += 256) acc += partials[j];
  s[tid] = acc; __syncthreads();
  #pragma unroll
  for (int st = 128; st; st >>= 1) { if (tid < st) s[tid] += s[tid + st]; __syncthreads(); }
  if (tid == 0) out[0] = s[0];
}

extern "C" void kernel_launch(void* const* d_in, const int* in_sizes, int n_in,
                              void* d_out, int out_size, void* d_ws, size_t ws_size,
                              hipStream_t stream) {
  const float* R      = (const float*)d_in[0];
  const int*   labels = (const int*)d_in[1];
  float* out = (float*)d_out;

  unsigned short* simq = (unsigned short*)d_ws;                          // 32 MB
  float* sq            = (float*)((char*)d_ws + (size_t)BB * BB * 2);    // 16 KB
  float* partials      = sq + BB;                                        // 16 KB

  splitsq<<<BB, 64, 0, stream>>>(R, sq);
  buildmask<<<64, 64, 0, stream>>>(labels);
  simgemm_wave<<<NTRI64, 64, 0, stream>>>(labels, sq, simq);
  rowproc6<<<BB / 4, 256, 0, stream>>>(simq, labels, partials);
  finalreduce<<<1, 256, 0, stream>>>(partials, out);
}